// Round 4
// baseline (4591.518 us; speedup 1.0000x reference)
//
#include <hip/hip_runtime.h>
#include <math.h>

#define BB 4
#define SS 2048
#define NH 8
#define HD 64
#define HID 512
#define EPSV 1e-5f

#define NROWS (BB * SS)                // 8192 (b,s) rows
#define QKV_ELEMS (BB * NH * SS * HD)  // 4,194,304
#define TOTROWS (BB * NH * SS)         // 65536 (b,h,s) rows
#define NJT 16                         // j-tiles of 128 in scores

typedef __attribute__((ext_vector_type(8))) short short8;
typedef __attribute__((ext_vector_type(4))) float f32x4;
typedef _Float16 half2v __attribute__((ext_vector_type(2)));

__device__ __forceinline__ unsigned short f2bf(float f) {
  unsigned u = __builtin_bit_cast(unsigned, f);
  u += 0x7fff + ((u >> 16) & 1);  // RNE
  return (unsigned short)(u >> 16);
}

// |a-b| for 2 packed f16, accumulated into f32 via v_dot2_f32_f16
__device__ __forceinline__ float absdiff2(unsigned qa, unsigned kb, float acc,
                                          half2v ones) {
  half2v d = __builtin_bit_cast(half2v, qa) - __builtin_bit_cast(half2v, kb);
  unsigned au = __builtin_bit_cast(unsigned, d) & 0x7fff7fffu;
  return __builtin_amdgcn_fdot2(__builtin_bit_cast(half2v, au), ones, acc, false);
}

// ---------------------------------------------------------------------------
// bf16-MFMA GEMM: C = A(M x 512) @ W(512 x 512)^T + bias.
// 128x128 tile, 256 threads (4 waves, 2x2 quadrants of 64x64), K-step 32.
// ABF16: A is bf16 (ushort) in gmem; else f32 (converted during staging).
// MODE 0: C f32 [m][n].
// MODE 2: C bf16 transposed per head [bh][d][s] (V -> PV B-operand).
// MODE 3: C f16 split-head [bh][s][d] (Q, K for scores).
// ---------------------------------------------------------------------------
template <int MODE, bool ABF16>
__global__ __launch_bounds__(256, 2) void gemm_bf16(const void* __restrict__ Ain,
                                                    const float* __restrict__ W,
                                                    const float* __restrict__ bias,
                                                    void* __restrict__ Cout) {
  __shared__ unsigned short As[128][40];  // 32 k + 8 pad
  __shared__ unsigned short Ws[128][40];
  const int m0 = blockIdx.y * 128;
  const int n0 = blockIdx.x * 128;
  const int tid = threadIdx.x;
  const int lane = tid & 63;
  const int w = tid >> 6;
  const int wr = w >> 1;
  const int wc = w & 1;
  const int l16 = lane & 15;
  const int lq = lane >> 4;

  f32x4 acc[4][4];
#pragma unroll
  for (int mr = 0; mr < 4; ++mr)
#pragma unroll
    for (int nc = 0; nc < 4; ++nc) acc[mr][nc] = (f32x4)0.f;

  for (int k0 = 0; k0 < HID; k0 += 32) {
    __syncthreads();
    if (ABF16) {
      const unsigned short* A = (const unsigned short*)Ain;
#pragma unroll
      for (int p = 0; p < 2; ++p) {
        int idx = tid + p * 256;
        int row = idx >> 2;
        int ch = (idx & 3) * 8;
        *(uint4*)&As[row][ch] = *(const uint4*)&A[(size_t)(m0 + row) * HID + k0 + ch];
      }
#pragma unroll
      for (int p = 0; p < 4; ++p) {
        int idx = tid + p * 256;
        int row = idx >> 3;
        int c4 = (idx & 7) * 4;
        float4 wv = *(const float4*)&W[(size_t)(n0 + row) * HID + k0 + c4];
        ushort4 wb = {f2bf(wv.x), f2bf(wv.y), f2bf(wv.z), f2bf(wv.w)};
        *(ushort4*)&Ws[row][c4] = wb;
      }
    } else {
      const float* A = (const float*)Ain;
#pragma unroll
      for (int p = 0; p < 4; ++p) {
        int idx = tid + p * 256;
        int row = idx >> 3;
        int c4 = (idx & 7) * 4;
        float4 av = *(const float4*)&A[(size_t)(m0 + row) * HID + k0 + c4];
        float4 wv = *(const float4*)&W[(size_t)(n0 + row) * HID + k0 + c4];
        ushort4 ab = {f2bf(av.x), f2bf(av.y), f2bf(av.z), f2bf(av.w)};
        ushort4 wb = {f2bf(wv.x), f2bf(wv.y), f2bf(wv.z), f2bf(wv.w)};
        *(ushort4*)&As[row][c4] = ab;
        *(ushort4*)&Ws[row][c4] = wb;
      }
    }
    __syncthreads();
    const int kb = lq * 8;
    short8 a[4], b[4];
#pragma unroll
    for (int mr = 0; mr < 4; ++mr)
      a[mr] = *(const short8*)&As[wr * 64 + mr * 16 + l16][kb];
#pragma unroll
    for (int nc = 0; nc < 4; ++nc)
      b[nc] = *(const short8*)&Ws[wc * 64 + nc * 16 + l16][kb];
#pragma unroll
    for (int mr = 0; mr < 4; ++mr)
#pragma unroll
      for (int nc = 0; nc < 4; ++nc)
        acc[mr][nc] = __builtin_amdgcn_mfma_f32_16x16x32_bf16(a[mr], b[nc], acc[mr][nc], 0, 0, 0);
  }

#pragma unroll
  for (int nc = 0; nc < 4; ++nc) {
    const int n = n0 + wc * 64 + nc * 16 + l16;
    const float bv = bias[n];
#pragma unroll
    for (int mr = 0; mr < 4; ++mr) {
#pragma unroll
      for (int jj = 0; jj < 4; ++jj) {
        const int m = m0 + wr * 64 + mr * 16 + lq * 4 + jj;
        float v = acc[mr][nc][jj] + bv;
        if (MODE == 0) {
          ((float*)Cout)[(size_t)m * HID + n] = v;
        } else if (MODE == 2) {  // bf16 [bh][d][s]
          const int b_ = m >> 11, s = m & (SS - 1);
          const int h = n >> 6, d = n & 63;
          ((unsigned short*)Cout)[(((size_t)(b_ * NH + h)) * HD + d) * SS + s] = f2bf(v);
        } else {  // MODE 3: f16 [bh][s][d]
          const int b_ = m >> 11, s = m & (SS - 1);
          const int h = n >> 6, d = n & 63;
          _Float16 hv = (_Float16)v;
          ((unsigned short*)Cout)[(((size_t)(b_ * NH + h)) * SS + s) * HD + d] =
              __builtin_bit_cast(unsigned short, hv);
        }
      }
    }
  }
}

// ---------------------------------------------------------------------------
// Scores pass: 64-row i-tile, j-tiles of 128, 4x8 micro-tile per thread.
// Q,K f16 [bh][s][d]. dist via packed-f16 sub + and-abs + v_dot2_f32_f16.
// Writes p' = exp(s - m_running) f32 into attn, msnap per (row, jtile128),
// final (m, sum) stats.
// ---------------------------------------------------------------------------
__global__ __launch_bounds__(256, 4) void scores_kernel(
    const unsigned short* __restrict__ Qh, const unsigned short* __restrict__ Kh,
    const int* __restrict__ mask, const float* __restrict__ temp,
    float* __restrict__ attn, float* __restrict__ stats,
    float* __restrict__ msnap) {
  __shared__ unsigned short Qs[64][72];   // 64 f16 + 8 pad (144B rows)
  __shared__ unsigned short Ks[128][72];
  __shared__ int Ms[128];

  const int bh = blockIdx.y;
  const int b = bh >> 3;
  const int h = bh & 7;
  const int i0 = blockIdx.x * 64;
  const int tid = threadIdx.x;
  const int ty = tid >> 4;  // 0..15 (rows ty+16r, r=0..3)
  const int tx = tid & 15;  // 0..15 (cols tx+16c, c=0..7)
  const float tmp = temp[h];
  const half2v ones = {(_Float16)1.0f, (_Float16)1.0f};

  const unsigned short* Qb = Qh + (size_t)bh * SS * HD;
  const unsigned short* Kb = Kh + (size_t)bh * SS * HD;
  float* attn_b = attn + (size_t)bh * SS * SS;

// stage Q tile once: 64 x 64 f16 = 512 uint4 chunks
#pragma unroll
  for (int p = 0; p < 2; ++p) {
    int idx = tid + p * 256;
    int row = idx >> 3;
    int ch = (idx & 7) * 8;
    *(uint4*)&Qs[row][ch] = *(const uint4*)&Qb[(size_t)(i0 + row) * HD + ch];
  }

  float m[4], sg[4];
#pragma unroll
  for (int r = 0; r < 4; ++r) {
    m[r] = -INFINITY;
    sg[r] = 0.f;
  }

  for (int j0 = 0; j0 < SS; j0 += 128) {
    __syncthreads();
#pragma unroll
    for (int p = 0; p < 4; ++p) {
      int idx = tid + p * 256;
      int row = idx >> 3;
      int ch = (idx & 7) * 8;
      *(uint4*)&Ks[row][ch] = *(const uint4*)&Kb[(size_t)(j0 + row) * HD + ch];
    }
    if (tid < 128) Ms[tid] = mask[b * SS + j0 + tid];
    __syncthreads();

    float dist[4][8];
#pragma unroll
    for (int r = 0; r < 4; ++r)
#pragma unroll
      for (int c = 0; c < 8; ++c) dist[r][c] = 0.f;

// 8 chunks of 8 d-values (4 dwords of packed f16)
#pragma unroll
    for (int k8 = 0; k8 < 8; ++k8) {
      uint4 q[4];
#pragma unroll
      for (int r = 0; r < 4; ++r) q[r] = *(const uint4*)&Qs[ty + 16 * r][k8 * 8];
#pragma unroll
      for (int chalf = 0; chalf < 2; ++chalf) {
        uint4 kx[4];
#pragma unroll
        for (int cc = 0; cc < 4; ++cc)
          kx[cc] = *(const uint4*)&Ks[tx + 16 * (chalf * 4 + cc)][k8 * 8];
#pragma unroll
        for (int r = 0; r < 4; ++r)
#pragma unroll
          for (int cc = 0; cc < 4; ++cc) {
            const int c = chalf * 4 + cc;
            float d = dist[r][c];
            d = absdiff2(q[r].x, kx[cc].x, d, ones);
            d = absdiff2(q[r].y, kx[cc].y, d, ones);
            d = absdiff2(q[r].z, kx[cc].z, d, ones);
            d = absdiff2(q[r].w, kx[cc].w, d, ones);
            dist[r][c] = d;
          }
      }
    }

    const int jt = j0 >> 7;
#pragma unroll
    for (int r = 0; r < 4; ++r) {
      float s[8];
      float rmax = -INFINITY;
#pragma unroll
      for (int c = 0; c < 8; ++c) {
        float sc = -dist[r][c] * tmp;
        if (Ms[tx + 16 * c] == 0) sc = -1e9f;
        s[c] = sc;
        rmax = fmaxf(rmax, sc);
      }
#pragma unroll
      for (int off = 1; off < 16; off <<= 1) rmax = fmaxf(rmax, __shfl_xor(rmax, off));
      const float mnew = fmaxf(m[r], rmax);
      const int i = i0 + ty + 16 * r;
      float* arow = attn_b + (size_t)i * SS + j0;
      float psum = 0.f;
#pragma unroll
      for (int c = 0; c < 8; ++c) {
        float pv = __expf(s[c] - mnew);
        psum += pv;
        arow[tx + 16 * c] = pv;  // store p'
      }
      sg[r] = sg[r] * __expf(m[r] - mnew) + psum;
      m[r] = mnew;
      if (tx == 0) msnap[((size_t)bh * NJT + jt) * SS + i] = mnew;
    }
  }

#pragma unroll
  for (int r = 0; r < 4; ++r) {
    float ssum = sg[r];
#pragma unroll
    for (int off = 1; off < 16; off <<= 1) ssum += __shfl_xor(ssum, off);
    if (tx == 0) {
      const int row = bh * SS + i0 + ty + 16 * r;
      stats[2 * row] = m[r];
      stats[2 * row + 1] = ssum;
    }
  }
}

// ---------------------------------------------------------------------------
// attn_pv: p = p' * exp(msnap - mfin) / sum ; rewrite attn f32 in place;
// PV via bf16 MFMA with pre-transposed V (Vt bf16 [bh][d][s]).
// 64x64 tiles for occupancy (19 KB LDS, grid 1024).
// ---------------------------------------------------------------------------
__global__ __launch_bounds__(256, 4) void attn_pv_kernel(
    const unsigned short* __restrict__ Vt, const float* __restrict__ stats,
    const float* __restrict__ msnap, float* __restrict__ attn,
    unsigned short* __restrict__ attn_out) {
  __shared__ unsigned short Ps[64][72];
  __shared__ unsigned short Vts[64][72];
  __shared__ float corr_s[64];

  const int bh = blockIdx.y;
  const int b = bh >> 3;
  const int h = bh & 7;
  const int i0 = blockIdx.x * 64;
  const int tid = threadIdx.x;
  const int lane = tid & 63;
  const int w = tid >> 6;
  const int wr = w >> 1;
  const int wc = w & 1;
  const int l16 = lane & 15;
  const int lq = lane >> 4;

  float* attn_b = attn + (size_t)bh * SS * SS;
  const unsigned short* Vtb = Vt + (size_t)bh * HD * SS;

  float mfin = 0.f, inv = 0.f;
  if (tid < 64) {
    const int row = bh * SS + i0 + tid;
    mfin = stats[2 * row];
    inv = 1.0f / stats[2 * row + 1];
  }

  f32x4 acc[2][2];
#pragma unroll
  for (int mr = 0; mr < 2; ++mr)
#pragma unroll
    for (int nc = 0; nc < 2; ++nc) acc[mr][nc] = (f32x4)0.f;

  for (int j0 = 0; j0 < SS; j0 += 64) {
    __syncthreads();
    if (tid < 64)
      corr_s[tid] =
          __expf(msnap[((size_t)bh * NJT + (j0 >> 7)) * SS + i0 + tid] - mfin) * inv;
// stage Vt tile: 64 d-rows x 64 j-cols bf16 = 512 uint4 chunks
#pragma unroll
    for (int p = 0; p < 2; ++p) {
      int idx = tid + p * 256;
      int row = idx >> 3;
      int ch = (idx & 7) * 8;
      *(uint4*)&Vts[row][ch] = *(const uint4*)&Vtb[(size_t)row * SS + j0 + ch];
    }
    __syncthreads();
// p-phase: 64x64 f32 RMW = 1024 float4
#pragma unroll
    for (int p = 0; p < 4; ++p) {
      int idx = tid + p * 256;
      int row = idx >> 4;
      int c4 = (idx & 15) * 4;
      float* ap = &attn_b[(size_t)(i0 + row) * SS + j0 + c4];
      float4 pv = *(float4*)ap;
      const float cr = corr_s[row];
      pv.x *= cr;
      pv.y *= cr;
      pv.z *= cr;
      pv.w *= cr;
      *(float4*)ap = pv;
      ushort4 pb = {f2bf(pv.x), f2bf(pv.y), f2bf(pv.z), f2bf(pv.w)};
      *(ushort4*)&Ps[row][c4] = pb;
    }
    __syncthreads();
// MFMA: out(64x64) += P(64x64) @ V(64x64)
#pragma unroll
    for (int ks = 0; ks < 2; ++ks) {
      const int kb = ks * 32 + lq * 8;
      short8 a[2], bf[2];
#pragma unroll
      for (int mr = 0; mr < 2; ++mr)
        a[mr] = *(const short8*)&Ps[wr * 32 + mr * 16 + l16][kb];
#pragma unroll
      for (int nc = 0; nc < 2; ++nc)
        bf[nc] = *(const short8*)&Vts[wc * 32 + nc * 16 + l16][kb];
#pragma unroll
      for (int mr = 0; mr < 2; ++mr)
#pragma unroll
        for (int nc = 0; nc < 2; ++nc)
          acc[mr][nc] = __builtin_amdgcn_mfma_f32_16x16x32_bf16(a[mr], bf[nc], acc[mr][nc], 0, 0, 0);
    }
  }

// epilogue: bf16 write [b, s, h*64 + d]
#pragma unroll
  for (int mr = 0; mr < 2; ++mr)
#pragma unroll
    for (int nc = 0; nc < 2; ++nc)
#pragma unroll
      for (int jj = 0; jj < 4; ++jj) {
        const int i = i0 + wr * 32 + mr * 16 + lq * 4 + jj;
        const int d = wc * 32 + nc * 16 + l16;
        attn_out[((size_t)(b * SS + i)) * HID + h * HD + d] = f2bf(acc[mr][nc][jj]);
      }
}

// ---------------------------------------------------------------------------
// Residual + LayerNorm
// ---------------------------------------------------------------------------
__global__ __launch_bounds__(256) void ln_kernel(const float* __restrict__ proj,
                                                 const float* __restrict__ query,
                                                 const float* __restrict__ gamma,
                                                 const float* __restrict__ beta,
                                                 float* __restrict__ out) {
  const int row = blockIdx.x;
  const int tid = threadIdx.x;

  float x[2];
  float sum = 0.f, sumsq = 0.f;
#pragma unroll
  for (int t = 0; t < 2; ++t) {
    const int c = tid + t * 256;
    float v = proj[(size_t)row * HID + c] + query[(size_t)row * HID + c];
    x[t] = v;
    sum += v;
    sumsq += v * v;
  }
#pragma unroll
  for (int off = 1; off < 64; off <<= 1) {
    sum += __shfl_xor(sum, off);
    sumsq += __shfl_xor(sumsq, off);
  }
  __shared__ float s1[4], s2[4];
  if ((tid & 63) == 0) {
    s1[tid >> 6] = sum;
    s2[tid >> 6] = sumsq;
  }
  __syncthreads();
  sum = s1[0] + s1[1] + s1[2] + s1[3];
  sumsq = s2[0] + s2[1] + s2[2] + s2[3];
  const float mu = sum * (1.f / HID);
  const float var = sumsq * (1.f / HID) - mu * mu;
  const float rstd = rsqrtf(var + EPSV);
#pragma unroll
  for (int t = 0; t < 2; ++t) {
    const int c = tid + t * 256;
    out[(size_t)row * HID + c] = (x[t] - mu) * rstd * gamma[c] + beta[c];
  }
}

// ---------------------------------------------------------------------------
extern "C" void kernel_launch(void* const* d_in, const int* in_sizes, int n_in,
                              void* d_out, int out_size, void* d_ws, size_t ws_size,
                              hipStream_t stream) {
  const float* query = (const float*)d_in[0];
  const float* key = (const float*)d_in[1];
  const float* value = (const float*)d_in[2];
  const int* mask = (const int*)d_in[3];
  const float* Wq = (const float*)d_in[4];
  const float* bq = (const float*)d_in[5];
  const float* Wk = (const float*)d_in[6];
  const float* bk = (const float*)d_in[7];
  const float* Wv = (const float*)d_in[8];
  const float* bv = (const float*)d_in[9];
  const float* Wo = (const float*)d_in[10];
  const float* bo = (const float*)d_in[11];
  const float* temp = (const float*)d_in[12];
  const float* gamma = (const float*)d_in[13];
  const float* beta = (const float*)d_in[14];

  float* out_final = (float*)d_out;                     // (B,S,HID)
  float* attn = (float*)d_out + (size_t)BB * SS * HID;  // (B,H,S,S)

  // workspace layout (36.5 MB total)
  unsigned short* Qh = (unsigned short*)d_ws;    // f16 [bh][s][d]   8MB
  unsigned short* Kh = Qh + QKV_ELEMS;           // f16 [bh][s][d]   8MB
  unsigned short* Vt = Kh + QKV_ELEMS;           // bf16 [bh][d][s]  8MB
  unsigned short* aout = Vt + QKV_ELEMS;         // bf16 [b*s][512]  8MB
  float* stats = (float*)(aout + QKV_ELEMS);     // 2 * TOTROWS      0.5MB
  float* msnap = stats + 2 * TOTROWS;            // NJT * TOTROWS    4MB
  float* proj = (float*)d_ws;                    // f32, aliases Qh+Kh (16MB)

  const dim3 blk(256);
  const dim3 ggrid(HID / 128, NROWS / 128);  // 4 x 64

  gemm_bf16<3, false><<<ggrid, blk, 0, stream>>>(query, Wq, bq, Qh);
  gemm_bf16<3, false><<<ggrid, blk, 0, stream>>>(key, Wk, bk, Kh);
  gemm_bf16<2, false><<<ggrid, blk, 0, stream>>>(value, Wv, bv, Vt);

  const dim3 sgrid(SS / 64, BB * NH);  // 32 x 32
  scores_kernel<<<sgrid, blk, 0, stream>>>(Qh, Kh, mask, temp, attn, stats, msnap);
  attn_pv_kernel<<<sgrid, blk, 0, stream>>>(Vt, stats, msnap, attn, aout);

  gemm_bf16<0, true><<<ggrid, blk, 0, stream>>>(aout, Wo, bo, proj);
  ln_kernel<<<NROWS, blk, 0, stream>>>(proj, query, gamma, beta, out_final);
}

// Round 5
// 1193.965 us; speedup vs baseline: 3.8456x; 3.8456x over previous
//
#include <hip/hip_runtime.h>
#include <math.h>

#define BB 4
#define SS 2048
#define NH 8
#define HD 64
#define HID 512
#define EPSV 1e-5f

#define NROWS (BB * SS)                // 8192 (b,s) rows
#define QKV_ELEMS (BB * NH * SS * HD)  // 4,194,304
#define TOTROWS (BB * NH * SS)         // 65536 (b,h,s) rows
#define NJT 32                         // j-tiles of 64 in scores

typedef __attribute__((ext_vector_type(8))) short short8;
typedef __attribute__((ext_vector_type(4))) float f32x4;
typedef _Float16 half2v __attribute__((ext_vector_type(2)));

__device__ __forceinline__ unsigned short f2bf(float f) {
  unsigned u = __builtin_bit_cast(unsigned, f);
  u += 0x7fff + ((u >> 16) & 1);  // RNE
  return (unsigned short)(u >> 16);
}

// |a-b| for 2 packed f16, accumulated into f32 via v_dot2_f32_f16
__device__ __forceinline__ float absdiff2(unsigned qa, unsigned kb, float acc,
                                          half2v ones) {
  half2v d = __builtin_bit_cast(half2v, qa) - __builtin_bit_cast(half2v, kb);
  unsigned au = __builtin_bit_cast(unsigned, d) & 0x7fff7fffu;
  return __builtin_amdgcn_fdot2(__builtin_bit_cast(half2v, au), ones, acc, false);
}

// ---------------------------------------------------------------------------
// bf16-MFMA GEMM: C = A(M x 512) @ W(512 x 512)^T + bias.
// 128x128 tile, 256 threads (4 waves, 2x2 quadrants of 64x64), K-step 32.
// ABF16: A is bf16 (ushort) in gmem; else f32 (converted during staging).
// MODE 0: C f32 [m][n].
// MODE 2: C bf16 transposed per head [bh][d][s] (V -> PV B-operand).
// MODE 3: C f16 split-head [bh][s][d] (Q, K for scores).
// ---------------------------------------------------------------------------
template <int MODE, bool ABF16>
__global__ __launch_bounds__(256, 2) void gemm_bf16(const void* __restrict__ Ain,
                                                    const float* __restrict__ W,
                                                    const float* __restrict__ bias,
                                                    void* __restrict__ Cout) {
  __shared__ unsigned short As[128][40];  // 32 k + 8 pad
  __shared__ unsigned short Ws[128][40];
  const int m0 = blockIdx.y * 128;
  const int n0 = blockIdx.x * 128;
  const int tid = threadIdx.x;
  const int lane = tid & 63;
  const int w = tid >> 6;
  const int wr = w >> 1;
  const int wc = w & 1;
  const int l16 = lane & 15;
  const int lq = lane >> 4;

  f32x4 acc[4][4];
#pragma unroll
  for (int mr = 0; mr < 4; ++mr)
#pragma unroll
    for (int nc = 0; nc < 4; ++nc) acc[mr][nc] = (f32x4)0.f;

  for (int k0 = 0; k0 < HID; k0 += 32) {
    __syncthreads();
    if (ABF16) {
      const unsigned short* A = (const unsigned short*)Ain;
#pragma unroll
      for (int p = 0; p < 2; ++p) {
        int idx = tid + p * 256;
        int row = idx >> 2;
        int ch = (idx & 3) * 8;
        *(uint4*)&As[row][ch] = *(const uint4*)&A[(size_t)(m0 + row) * HID + k0 + ch];
      }
#pragma unroll
      for (int p = 0; p < 4; ++p) {
        int idx = tid + p * 256;
        int row = idx >> 3;
        int c4 = (idx & 7) * 4;
        float4 wv = *(const float4*)&W[(size_t)(n0 + row) * HID + k0 + c4];
        ushort4 wb = {f2bf(wv.x), f2bf(wv.y), f2bf(wv.z), f2bf(wv.w)};
        *(ushort4*)&Ws[row][c4] = wb;
      }
    } else {
      const float* A = (const float*)Ain;
#pragma unroll
      for (int p = 0; p < 4; ++p) {
        int idx = tid + p * 256;
        int row = idx >> 3;
        int c4 = (idx & 7) * 4;
        float4 av = *(const float4*)&A[(size_t)(m0 + row) * HID + k0 + c4];
        float4 wv = *(const float4*)&W[(size_t)(n0 + row) * HID + k0 + c4];
        ushort4 ab = {f2bf(av.x), f2bf(av.y), f2bf(av.z), f2bf(av.w)};
        ushort4 wb = {f2bf(wv.x), f2bf(wv.y), f2bf(wv.z), f2bf(wv.w)};
        *(ushort4*)&As[row][c4] = ab;
        *(ushort4*)&Ws[row][c4] = wb;
      }
    }
    __syncthreads();
    const int kb = lq * 8;
    short8 a[4], b[4];
#pragma unroll
    for (int mr = 0; mr < 4; ++mr)
      a[mr] = *(const short8*)&As[wr * 64 + mr * 16 + l16][kb];
#pragma unroll
    for (int nc = 0; nc < 4; ++nc)
      b[nc] = *(const short8*)&Ws[wc * 64 + nc * 16 + l16][kb];
#pragma unroll
    for (int mr = 0; mr < 4; ++mr)
#pragma unroll
      for (int nc = 0; nc < 4; ++nc)
        acc[mr][nc] = __builtin_amdgcn_mfma_f32_16x16x32_bf16(a[mr], b[nc], acc[mr][nc], 0, 0, 0);
  }

#pragma unroll
  for (int nc = 0; nc < 4; ++nc) {
    const int n = n0 + wc * 64 + nc * 16 + l16;
    const float bv = bias[n];
#pragma unroll
    for (int mr = 0; mr < 4; ++mr) {
#pragma unroll
      for (int jj = 0; jj < 4; ++jj) {
        const int m = m0 + wr * 64 + mr * 16 + lq * 4 + jj;
        float v = acc[mr][nc][jj] + bv;
        if (MODE == 0) {
          ((float*)Cout)[(size_t)m * HID + n] = v;
        } else if (MODE == 2) {  // bf16 [bh][d][s]
          const int b_ = m >> 11, s = m & (SS - 1);
          const int h = n >> 6, d = n & 63;
          ((unsigned short*)Cout)[(((size_t)(b_ * NH + h)) * HD + d) * SS + s] = f2bf(v);
        } else {  // MODE 3: f16 [bh][s][d]
          const int b_ = m >> 11, s = m & (SS - 1);
          const int h = n >> 6, d = n & 63;
          _Float16 hv = (_Float16)v;
          ((unsigned short*)Cout)[(((size_t)(b_ * NH + h)) * SS + s) * HD + d] =
              __builtin_bit_cast(unsigned short, hv);
        }
      }
    }
  }
}

// ---------------------------------------------------------------------------
// Scores pass: 64-row i-tile, 64-col j-tiles, 4x4 micro-tile per thread.
// Q,K f16 [bh][s][d]. dist via packed-f16 sub + and-abs + v_dot2_f32_f16.
// Live regs kept ~55 (q[4] uint4 + single kx + dist[4][4]) - NO spill.
// Writes p' = exp(s - m_running) f32 into attn, msnap per (row, jtile64),
// final (m, sum) stats.
// ---------------------------------------------------------------------------
__global__ __launch_bounds__(256) void scores_kernel(
    const unsigned short* __restrict__ Qh, const unsigned short* __restrict__ Kh,
    const int* __restrict__ mask, const float* __restrict__ temp,
    float* __restrict__ attn, float* __restrict__ stats,
    float* __restrict__ msnap) {
  __shared__ unsigned short Qs[64][72];  // 64 f16 + 8 pad (144B rows)
  __shared__ unsigned short Ks[64][72];
  __shared__ int Ms[64];

  const int bh = blockIdx.y;
  const int b = bh >> 3;
  const int h = bh & 7;
  const int i0 = blockIdx.x * 64;
  const int tid = threadIdx.x;
  const int ty = tid >> 4;  // 0..15 (rows ty+16r, r=0..3)
  const int tx = tid & 15;  // 0..15 (cols tx+16c, c=0..3)
  const float tmp = temp[h];
  const half2v ones = {(_Float16)1.0f, (_Float16)1.0f};

  const unsigned short* Qb = Qh + (size_t)bh * SS * HD;
  const unsigned short* Kb = Kh + (size_t)bh * SS * HD;
  float* attn_b = attn + (size_t)bh * SS * SS;

// stage Q tile once: 64 x 64 f16 = 512 uint4 chunks
#pragma unroll
  for (int p = 0; p < 2; ++p) {
    int idx = tid + p * 256;
    int row = idx >> 3;
    int ch = (idx & 7) * 8;
    *(uint4*)&Qs[row][ch] = *(const uint4*)&Qb[(size_t)(i0 + row) * HD + ch];
  }

  float m[4], sg[4];
#pragma unroll
  for (int r = 0; r < 4; ++r) {
    m[r] = -INFINITY;
    sg[r] = 0.f;
  }

  for (int j0 = 0; j0 < SS; j0 += 64) {
    __syncthreads();
#pragma unroll
    for (int p = 0; p < 2; ++p) {
      int idx = tid + p * 256;
      int row = idx >> 3;
      int ch = (idx & 7) * 8;
      *(uint4*)&Ks[row][ch] = *(const uint4*)&Kb[(size_t)(j0 + row) * HD + ch];
    }
    if (tid < 64) Ms[tid] = mask[b * SS + j0 + tid];
    __syncthreads();

    float dist[4][4];
#pragma unroll
    for (int r = 0; r < 4; ++r)
#pragma unroll
      for (int c = 0; c < 4; ++c) dist[r][c] = 0.f;

// 8 chunks of 8 d-values (uint4 = 4 dwords of packed f16)
#pragma unroll
    for (int k8 = 0; k8 < 8; ++k8) {
      uint4 q[4];
#pragma unroll
      for (int r = 0; r < 4; ++r) q[r] = *(const uint4*)&Qs[ty + 16 * r][k8 * 8];
#pragma unroll
      for (int c = 0; c < 4; ++c) {
        const uint4 kx = *(const uint4*)&Ks[tx + 16 * c][k8 * 8];
#pragma unroll
        for (int r = 0; r < 4; ++r) {
          float d = dist[r][c];
          d = absdiff2(q[r].x, kx.x, d, ones);
          d = absdiff2(q[r].y, kx.y, d, ones);
          d = absdiff2(q[r].z, kx.z, d, ones);
          d = absdiff2(q[r].w, kx.w, d, ones);
          dist[r][c] = d;
        }
      }
    }

    const int jt = j0 >> 6;
#pragma unroll
    for (int r = 0; r < 4; ++r) {
      float s[4];
      float rmax = -INFINITY;
#pragma unroll
      for (int c = 0; c < 4; ++c) {
        float sc = -dist[r][c] * tmp;
        if (Ms[tx + 16 * c] == 0) sc = -1e9f;
        s[c] = sc;
        rmax = fmaxf(rmax, sc);
      }
#pragma unroll
      for (int off = 1; off < 16; off <<= 1) rmax = fmaxf(rmax, __shfl_xor(rmax, off));
      const float mnew = fmaxf(m[r], rmax);
      const int i = i0 + ty + 16 * r;
      float* arow = attn_b + (size_t)i * SS + j0;
      float psum = 0.f;
#pragma unroll
      for (int c = 0; c < 4; ++c) {
        float pv = __expf(s[c] - mnew);
        psum += pv;
        arow[tx + 16 * c] = pv;  // store p'
      }
      sg[r] = sg[r] * __expf(m[r] - mnew) + psum;
      m[r] = mnew;
      if (tx == 0) msnap[((size_t)bh * NJT + jt) * SS + i] = mnew;
    }
  }

#pragma unroll
  for (int r = 0; r < 4; ++r) {
    float ssum = sg[r];
#pragma unroll
    for (int off = 1; off < 16; off <<= 1) ssum += __shfl_xor(ssum, off);
    if (tx == 0) {
      const int row = bh * SS + i0 + ty + 16 * r;
      stats[2 * row] = m[r];
      stats[2 * row + 1] = ssum;
    }
  }
}

// ---------------------------------------------------------------------------
// attn_pv: p = p' * exp(msnap - mfin) / sum ; rewrite attn f32 in place;
// PV via bf16 MFMA with pre-transposed V (Vt bf16 [bh][d][s]).
// 64x64 tiles for occupancy (19 KB LDS, grid 1024).
// ---------------------------------------------------------------------------
__global__ __launch_bounds__(256, 4) void attn_pv_kernel(
    const unsigned short* __restrict__ Vt, const float* __restrict__ stats,
    const float* __restrict__ msnap, float* __restrict__ attn,
    unsigned short* __restrict__ attn_out) {
  __shared__ unsigned short Ps[64][72];
  __shared__ unsigned short Vts[64][72];
  __shared__ float corr_s[64];

  const int bh = blockIdx.y;
  const int b = bh >> 3;
  const int h = bh & 7;
  const int i0 = blockIdx.x * 64;
  const int tid = threadIdx.x;
  const int lane = tid & 63;
  const int w = tid >> 6;
  const int wr = w >> 1;
  const int wc = w & 1;
  const int l16 = lane & 15;
  const int lq = lane >> 4;

  float* attn_b = attn + (size_t)bh * SS * SS;
  const unsigned short* Vtb = Vt + (size_t)bh * HD * SS;

  float mfin = 0.f, inv = 0.f;
  if (tid < 64) {
    const int row = bh * SS + i0 + tid;
    mfin = stats[2 * row];
    inv = 1.0f / stats[2 * row + 1];
  }

  f32x4 acc[2][2];
#pragma unroll
  for (int mr = 0; mr < 2; ++mr)
#pragma unroll
    for (int nc = 0; nc < 2; ++nc) acc[mr][nc] = (f32x4)0.f;

  for (int j0 = 0; j0 < SS; j0 += 64) {
    __syncthreads();
    if (tid < 64)
      corr_s[tid] =
          __expf(msnap[((size_t)bh * NJT + (j0 >> 6)) * SS + i0 + tid] - mfin) * inv;
// stage Vt tile: 64 d-rows x 64 j-cols bf16 = 512 uint4 chunks
#pragma unroll
    for (int p = 0; p < 2; ++p) {
      int idx = tid + p * 256;
      int row = idx >> 3;
      int ch = (idx & 7) * 8;
      *(uint4*)&Vts[row][ch] = *(const uint4*)&Vtb[(size_t)row * SS + j0 + ch];
    }
    __syncthreads();
// p-phase: 64x64 f32 RMW = 1024 float4
#pragma unroll
    for (int p = 0; p < 4; ++p) {
      int idx = tid + p * 256;
      int row = idx >> 4;
      int c4 = (idx & 15) * 4;
      float* ap = &attn_b[(size_t)(i0 + row) * SS + j0 + c4];
      float4 pv = *(float4*)ap;
      const float cr = corr_s[row];
      pv.x *= cr;
      pv.y *= cr;
      pv.z *= cr;
      pv.w *= cr;
      *(float4*)ap = pv;
      ushort4 pb = {f2bf(pv.x), f2bf(pv.y), f2bf(pv.z), f2bf(pv.w)};
      *(ushort4*)&Ps[row][c4] = pb;
    }
    __syncthreads();
// MFMA: out(64x64) += P(64x64) @ V(64x64)
#pragma unroll
    for (int ks = 0; ks < 2; ++ks) {
      const int kb = ks * 32 + lq * 8;
      short8 a[2], bf[2];
#pragma unroll
      for (int mr = 0; mr < 2; ++mr)
        a[mr] = *(const short8*)&Ps[wr * 32 + mr * 16 + l16][kb];
#pragma unroll
      for (int nc = 0; nc < 2; ++nc)
        bf[nc] = *(const short8*)&Vts[wc * 32 + nc * 16 + l16][kb];
#pragma unroll
      for (int mr = 0; mr < 2; ++mr)
#pragma unroll
        for (int nc = 0; nc < 2; ++nc)
          acc[mr][nc] = __builtin_amdgcn_mfma_f32_16x16x32_bf16(a[mr], bf[nc], acc[mr][nc], 0, 0, 0);
    }
  }

// epilogue: bf16 write [b, s, h*64 + d]
#pragma unroll
  for (int mr = 0; mr < 2; ++mr)
#pragma unroll
    for (int nc = 0; nc < 2; ++nc)
#pragma unroll
      for (int jj = 0; jj < 4; ++jj) {
        const int i = i0 + wr * 32 + mr * 16 + lq * 4 + jj;
        const int d = wc * 32 + nc * 16 + l16;
        attn_out[((size_t)(b * SS + i)) * HID + h * HD + d] = f2bf(acc[mr][nc][jj]);
      }
}

// ---------------------------------------------------------------------------
// Residual + LayerNorm
// ---------------------------------------------------------------------------
__global__ __launch_bounds__(256) void ln_kernel(const float* __restrict__ proj,
                                                 const float* __restrict__ query,
                                                 const float* __restrict__ gamma,
                                                 const float* __restrict__ beta,
                                                 float* __restrict__ out) {
  const int row = blockIdx.x;
  const int tid = threadIdx.x;

  float x[2];
  float sum = 0.f, sumsq = 0.f;
#pragma unroll
  for (int t = 0; t < 2; ++t) {
    const int c = tid + t * 256;
    float v = proj[(size_t)row * HID + c] + query[(size_t)row * HID + c];
    x[t] = v;
    sum += v;
    sumsq += v * v;
  }
#pragma unroll
  for (int off = 1; off < 64; off <<= 1) {
    sum += __shfl_xor(sum, off);
    sumsq += __shfl_xor(sumsq, off);
  }
  __shared__ float s1[4], s2[4];
  if ((tid & 63) == 0) {
    s1[tid >> 6] = sum;
    s2[tid >> 6] = sumsq;
  }
  __syncthreads();
  sum = s1[0] + s1[1] + s1[2] + s1[3];
  sumsq = s2[0] + s2[1] + s2[2] + s2[3];
  const float mu = sum * (1.f / HID);
  const float var = sumsq * (1.f / HID) - mu * mu;
  const float rstd = rsqrtf(var + EPSV);
#pragma unroll
  for (int t = 0; t < 2; ++t) {
    const int c = tid + t * 256;
    out[(size_t)row * HID + c] = (x[t] - mu) * rstd * gamma[c] + beta[c];
  }
}

// ---------------------------------------------------------------------------
extern "C" void kernel_launch(void* const* d_in, const int* in_sizes, int n_in,
                              void* d_out, int out_size, void* d_ws, size_t ws_size,
                              hipStream_t stream) {
  const float* query = (const float*)d_in[0];
  const float* key = (const float*)d_in[1];
  const float* value = (const float*)d_in[2];
  const int* mask = (const int*)d_in[3];
  const float* Wq = (const float*)d_in[4];
  const float* bq = (const float*)d_in[5];
  const float* Wk = (const float*)d_in[6];
  const float* bk = (const float*)d_in[7];
  const float* Wv = (const float*)d_in[8];
  const float* bv = (const float*)d_in[9];
  const float* Wo = (const float*)d_in[10];
  const float* bo = (const float*)d_in[11];
  const float* temp = (const float*)d_in[12];
  const float* gamma = (const float*)d_in[13];
  const float* beta = (const float*)d_in[14];

  float* out_final = (float*)d_out;                     // (B,S,HID)
  float* attn = (float*)d_out + (size_t)BB * SS * HID;  // (B,H,S,S)

  // workspace layout (40.5 MB total)
  unsigned short* Qh = (unsigned short*)d_ws;    // f16 [bh][s][d]   8MB
  unsigned short* Kh = Qh + QKV_ELEMS;           // f16 [bh][s][d]   8MB
  unsigned short* Vt = Kh + QKV_ELEMS;           // bf16 [bh][d][s]  8MB
  unsigned short* aout = Vt + QKV_ELEMS;         // bf16 [b*s][512]  8MB
  float* stats = (float*)(aout + QKV_ELEMS);     // 2 * TOTROWS      0.5MB
  float* msnap = stats + 2 * TOTROWS;            // NJT * TOTROWS    8MB
  float* proj = (float*)d_ws;                    // f32, aliases Qh+Kh (16MB)

  const dim3 blk(256);
  const dim3 ggrid(HID / 128, NROWS / 128);  // 4 x 64

  gemm_bf16<3, false><<<ggrid, blk, 0, stream>>>(query, Wq, bq, Qh);
  gemm_bf16<3, false><<<ggrid, blk, 0, stream>>>(key, Wk, bk, Kh);
  gemm_bf16<2, false><<<ggrid, blk, 0, stream>>>(value, Wv, bv, Vt);

  const dim3 sgrid(SS / 64, BB * NH);  // 32 x 32
  scores_kernel<<<sgrid, blk, 0, stream>>>(Qh, Kh, mask, temp, attn, stats, msnap);
  attn_pv_kernel<<<sgrid, blk, 0, stream>>>(Vt, stats, msnap, attn, aout);

  gemm_bf16<0, true><<<ggrid, blk, 0, stream>>>(aout, Wo, bo, proj);
  ln_kernel<<<NROWS, blk, 0, stream>>>(proj, query, gamma, beta, out_final);
}

// Round 6
// 928.434 us; speedup vs baseline: 4.9454x; 1.2860x over previous
//
#include <hip/hip_runtime.h>
#include <math.h>

#define BB 4
#define SS 2048
#define NH 8
#define HD 64
#define HID 512
#define EPSV 1e-5f

#define NROWS (BB * SS)                // 8192 (b,s) rows
#define QKV_ELEMS (BB * NH * SS * HD)  // 4,194,304
#define TOTROWS (BB * NH * SS)         // 65536 (b,h,s) rows
#define NJT 32                         // j-tiles of 64 in scores

typedef __attribute__((ext_vector_type(8))) short short8;
typedef __attribute__((ext_vector_type(4))) float f32x4;
typedef _Float16 half2v __attribute__((ext_vector_type(2)));

__device__ __forceinline__ unsigned short f2bf(float f) {
  unsigned u = __builtin_bit_cast(unsigned, f);
  u += 0x7fff + ((u >> 16) & 1);  // RNE
  return (unsigned short)(u >> 16);
}

// |a-b| for 2 packed f16, accumulated into f32 via v_dot2_f32_f16
__device__ __forceinline__ float absdiff2(unsigned qa, unsigned kb, float acc,
                                          half2v ones) {
  half2v d = __builtin_bit_cast(half2v, qa) - __builtin_bit_cast(half2v, kb);
  unsigned au = __builtin_bit_cast(unsigned, d) & 0x7fff7fffu;
  return __builtin_amdgcn_fdot2(__builtin_bit_cast(half2v, au), ones, acc, false);
}

// ---------------------------------------------------------------------------
// bf16-MFMA GEMM: C = A(M x 512) @ W(512 x 512)^T + bias.
// 128x128 tile, 256 threads (4 waves, 2x2 quadrants of 64x64), K-step 32.
// ABF16: A is bf16 (ushort) in gmem; else f32 (converted during staging).
// MODE 0: C f32 [m][n].
// MODE 2: C bf16 transposed per head [bh][d][s] (V -> PV B-operand).
// MODE 3: C f16 split-head [bh][s][d] (Q, K for scores).
// ---------------------------------------------------------------------------
template <int MODE, bool ABF16>
__global__ __launch_bounds__(256, 2) void gemm_bf16(const void* __restrict__ Ain,
                                                    const float* __restrict__ W,
                                                    const float* __restrict__ bias,
                                                    void* __restrict__ Cout) {
  __shared__ unsigned short As[128][40];  // 32 k + 8 pad
  __shared__ unsigned short Ws[128][40];
  const int m0 = blockIdx.y * 128;
  const int n0 = blockIdx.x * 128;
  const int tid = threadIdx.x;
  const int lane = tid & 63;
  const int w = tid >> 6;
  const int wr = w >> 1;
  const int wc = w & 1;
  const int l16 = lane & 15;
  const int lq = lane >> 4;

  f32x4 acc[4][4];
#pragma unroll
  for (int mr = 0; mr < 4; ++mr)
#pragma unroll
    for (int nc = 0; nc < 4; ++nc) acc[mr][nc] = (f32x4)0.f;

  for (int k0 = 0; k0 < HID; k0 += 32) {
    __syncthreads();
    if (ABF16) {
      const unsigned short* A = (const unsigned short*)Ain;
#pragma unroll
      for (int p = 0; p < 2; ++p) {
        int idx = tid + p * 256;
        int row = idx >> 2;
        int ch = (idx & 3) * 8;
        *(uint4*)&As[row][ch] = *(const uint4*)&A[(size_t)(m0 + row) * HID + k0 + ch];
      }
#pragma unroll
      for (int p = 0; p < 4; ++p) {
        int idx = tid + p * 256;
        int row = idx >> 3;
        int c4 = (idx & 7) * 4;
        float4 wv = *(const float4*)&W[(size_t)(n0 + row) * HID + k0 + c4];
        ushort4 wb = {f2bf(wv.x), f2bf(wv.y), f2bf(wv.z), f2bf(wv.w)};
        *(ushort4*)&Ws[row][c4] = wb;
      }
    } else {
      const float* A = (const float*)Ain;
#pragma unroll
      for (int p = 0; p < 4; ++p) {
        int idx = tid + p * 256;
        int row = idx >> 3;
        int c4 = (idx & 7) * 4;
        float4 av = *(const float4*)&A[(size_t)(m0 + row) * HID + k0 + c4];
        float4 wv = *(const float4*)&W[(size_t)(n0 + row) * HID + k0 + c4];
        ushort4 ab = {f2bf(av.x), f2bf(av.y), f2bf(av.z), f2bf(av.w)};
        ushort4 wb = {f2bf(wv.x), f2bf(wv.y), f2bf(wv.z), f2bf(wv.w)};
        *(ushort4*)&As[row][c4] = ab;
        *(ushort4*)&Ws[row][c4] = wb;
      }
    }
    __syncthreads();
    const int kb = lq * 8;
    short8 a[4], b[4];
#pragma unroll
    for (int mr = 0; mr < 4; ++mr)
      a[mr] = *(const short8*)&As[wr * 64 + mr * 16 + l16][kb];
#pragma unroll
    for (int nc = 0; nc < 4; ++nc)
      b[nc] = *(const short8*)&Ws[wc * 64 + nc * 16 + l16][kb];
#pragma unroll
    for (int mr = 0; mr < 4; ++mr)
#pragma unroll
      for (int nc = 0; nc < 4; ++nc)
        acc[mr][nc] = __builtin_amdgcn_mfma_f32_16x16x32_bf16(a[mr], b[nc], acc[mr][nc], 0, 0, 0);
  }

#pragma unroll
  for (int nc = 0; nc < 4; ++nc) {
    const int n = n0 + wc * 64 + nc * 16 + l16;
    const float bv = bias[n];
#pragma unroll
    for (int mr = 0; mr < 4; ++mr) {
#pragma unroll
      for (int jj = 0; jj < 4; ++jj) {
        const int m = m0 + wr * 64 + mr * 16 + lq * 4 + jj;
        float v = acc[mr][nc][jj] + bv;
        if (MODE == 0) {
          ((float*)Cout)[(size_t)m * HID + n] = v;
        } else if (MODE == 2) {  // bf16 [bh][d][s]
          const int b_ = m >> 11, s = m & (SS - 1);
          const int h = n >> 6, d = n & 63;
          ((unsigned short*)Cout)[(((size_t)(b_ * NH + h)) * HD + d) * SS + s] = f2bf(v);
        } else {  // MODE 3: f16 [bh][s][d]
          const int b_ = m >> 11, s = m & (SS - 1);
          const int h = n >> 6, d = n & 63;
          _Float16 hv = (_Float16)v;
          ((unsigned short*)Cout)[(((size_t)(b_ * NH + h)) * SS + s) * HD + d] =
              __builtin_bit_cast(unsigned short, hv);
        }
      }
    }
  }
}

// ---------------------------------------------------------------------------
// Scores pass: 64-row i-tile, 64-col j-tiles, 4x4 micro-tile per thread.
// Q,K f16 [bh][s][d]. dist via packed-f16 sub + and-abs + v_dot2_f32_f16.
// __launch_bounds__(256,5): cap VGPR ~102 (live set ~70, no spill) so 5
// waves/SIMD hide LDS/VALU latency. unroll 2 on k8 stops load-batching.
// ---------------------------------------------------------------------------
__global__ __launch_bounds__(256, 5) void scores_kernel(
    const unsigned short* __restrict__ Qh, const unsigned short* __restrict__ Kh,
    const int* __restrict__ mask, const float* __restrict__ temp,
    float* __restrict__ attn, float* __restrict__ stats,
    float* __restrict__ msnap) {
  __shared__ unsigned short Qs[64][72];  // 64 f16 + 8 pad (144B rows)
  __shared__ unsigned short Ks[64][72];
  __shared__ int Ms[64];

  const int bh = blockIdx.y;
  const int b = bh >> 3;
  const int h = bh & 7;
  const int i0 = blockIdx.x * 64;
  const int tid = threadIdx.x;
  const int ty = tid >> 4;  // 0..15 (rows ty+16r, r=0..3)
  const int tx = tid & 15;  // 0..15 (cols tx+16c, c=0..3)
  const float tmp = temp[h];
  const half2v ones = {(_Float16)1.0f, (_Float16)1.0f};

  const unsigned short* Qb = Qh + (size_t)bh * SS * HD;
  const unsigned short* Kb = Kh + (size_t)bh * SS * HD;
  float* attn_b = attn + (size_t)bh * SS * SS;

// stage Q tile once: 64 x 64 f16 = 512 uint4 chunks
#pragma unroll
  for (int p = 0; p < 2; ++p) {
    int idx = tid + p * 256;
    int row = idx >> 3;
    int ch = (idx & 7) * 8;
    *(uint4*)&Qs[row][ch] = *(const uint4*)&Qb[(size_t)(i0 + row) * HD + ch];
  }

  float m[4], sg[4];
#pragma unroll
  for (int r = 0; r < 4; ++r) {
    m[r] = -INFINITY;
    sg[r] = 0.f;
  }

  for (int j0 = 0; j0 < SS; j0 += 64) {
    __syncthreads();
#pragma unroll
    for (int p = 0; p < 2; ++p) {
      int idx = tid + p * 256;
      int row = idx >> 3;
      int ch = (idx & 7) * 8;
      *(uint4*)&Ks[row][ch] = *(const uint4*)&Kb[(size_t)(j0 + row) * HD + ch];
    }
    if (tid < 64) Ms[tid] = mask[b * SS + j0 + tid];
    __syncthreads();

    float dist[4][4];
#pragma unroll
    for (int r = 0; r < 4; ++r)
#pragma unroll
      for (int c = 0; c < 4; ++c) dist[r][c] = 0.f;

// 8 chunks of 8 d-values (uint4 = 4 dwords of packed f16); unroll 2 keeps
// the load batch (and VGPR footprint) small.
#pragma unroll 2
    for (int k8 = 0; k8 < 8; ++k8) {
      uint4 q[4];
#pragma unroll
      for (int r = 0; r < 4; ++r) q[r] = *(const uint4*)&Qs[ty + 16 * r][k8 * 8];
#pragma unroll
      for (int c = 0; c < 4; ++c) {
        const uint4 kx = *(const uint4*)&Ks[tx + 16 * c][k8 * 8];
#pragma unroll
        for (int r = 0; r < 4; ++r) {
          float d = dist[r][c];
          d = absdiff2(q[r].x, kx.x, d, ones);
          d = absdiff2(q[r].y, kx.y, d, ones);
          d = absdiff2(q[r].z, kx.z, d, ones);
          d = absdiff2(q[r].w, kx.w, d, ones);
          dist[r][c] = d;
        }
      }
    }

    int msk[4];
#pragma unroll
    for (int c = 0; c < 4; ++c) msk[c] = Ms[tx + 16 * c];

    const int jt = j0 >> 6;
#pragma unroll
    for (int r = 0; r < 4; ++r) {
      float s[4];
      float rmax = -INFINITY;
#pragma unroll
      for (int c = 0; c < 4; ++c) {
        float sc = -dist[r][c] * tmp;
        if (msk[c] == 0) sc = -1e9f;
        s[c] = sc;
        rmax = fmaxf(rmax, sc);
      }
#pragma unroll
      for (int off = 1; off < 16; off <<= 1) rmax = fmaxf(rmax, __shfl_xor(rmax, off));
      const float mnew = fmaxf(m[r], rmax);
      const int i = i0 + ty + 16 * r;
      float* arow = attn_b + (size_t)i * SS + j0;
      float psum = 0.f;
#pragma unroll
      for (int c = 0; c < 4; ++c) {
        float pv = __expf(s[c] - mnew);
        psum += pv;
        arow[tx + 16 * c] = pv;  // store p'
      }
      sg[r] = sg[r] * __expf(m[r] - mnew) + psum;
      m[r] = mnew;
      if (tx == 0) msnap[((size_t)bh * NJT + jt) * SS + i] = mnew;
    }
  }

#pragma unroll
  for (int r = 0; r < 4; ++r) {
    float ssum = sg[r];
#pragma unroll
    for (int off = 1; off < 16; off <<= 1) ssum += __shfl_xor(ssum, off);
    if (tx == 0) {
      const int row = bh * SS + i0 + ty + 16 * r;
      stats[2 * row] = m[r];
      stats[2 * row + 1] = ssum;
    }
  }
}

// ---------------------------------------------------------------------------
// attn_pv: p = p' * exp(msnap - mfin) / sum ; rewrite attn f32 in place;
// PV via bf16 MFMA with pre-transposed V (Vt bf16 [bh][d][s]).
// 64x64 tiles for occupancy (19 KB LDS, grid 1024).
// ---------------------------------------------------------------------------
__global__ __launch_bounds__(256, 4) void attn_pv_kernel(
    const unsigned short* __restrict__ Vt, const float* __restrict__ stats,
    const float* __restrict__ msnap, float* __restrict__ attn,
    unsigned short* __restrict__ attn_out) {
  __shared__ unsigned short Ps[64][72];
  __shared__ unsigned short Vts[64][72];
  __shared__ float corr_s[64];

  const int bh = blockIdx.y;
  const int b = bh >> 3;
  const int h = bh & 7;
  const int i0 = blockIdx.x * 64;
  const int tid = threadIdx.x;
  const int lane = tid & 63;
  const int w = tid >> 6;
  const int wr = w >> 1;
  const int wc = w & 1;
  const int l16 = lane & 15;
  const int lq = lane >> 4;

  float* attn_b = attn + (size_t)bh * SS * SS;
  const unsigned short* Vtb = Vt + (size_t)bh * HD * SS;

  float mfin = 0.f, inv = 0.f;
  if (tid < 64) {
    const int row = bh * SS + i0 + tid;
    mfin = stats[2 * row];
    inv = 1.0f / stats[2 * row + 1];
  }

  f32x4 acc[2][2];
#pragma unroll
  for (int mr = 0; mr < 2; ++mr)
#pragma unroll
    for (int nc = 0; nc < 2; ++nc) acc[mr][nc] = (f32x4)0.f;

  for (int j0 = 0; j0 < SS; j0 += 64) {
    __syncthreads();
    if (tid < 64)
      corr_s[tid] =
          __expf(msnap[((size_t)bh * NJT + (j0 >> 6)) * SS + i0 + tid] - mfin) * inv;
// stage Vt tile: 64 d-rows x 64 j-cols bf16 = 512 uint4 chunks
#pragma unroll
    for (int p = 0; p < 2; ++p) {
      int idx = tid + p * 256;
      int row = idx >> 3;
      int ch = (idx & 7) * 8;
      *(uint4*)&Vts[row][ch] = *(const uint4*)&Vtb[(size_t)row * SS + j0 + ch];
    }
    __syncthreads();
// p-phase: 64x64 f32 RMW = 1024 float4
#pragma unroll
    for (int p = 0; p < 4; ++p) {
      int idx = tid + p * 256;
      int row = idx >> 4;
      int c4 = (idx & 15) * 4;
      float* ap = &attn_b[(size_t)(i0 + row) * SS + j0 + c4];
      float4 pv = *(float4*)ap;
      const float cr = corr_s[row];
      pv.x *= cr;
      pv.y *= cr;
      pv.z *= cr;
      pv.w *= cr;
      *(float4*)ap = pv;
      ushort4 pb = {f2bf(pv.x), f2bf(pv.y), f2bf(pv.z), f2bf(pv.w)};
      *(ushort4*)&Ps[row][c4] = pb;
    }
    __syncthreads();
// MFMA: out(64x64) += P(64x64) @ V(64x64)
#pragma unroll
    for (int ks = 0; ks < 2; ++ks) {
      const int kb = ks * 32 + lq * 8;
      short8 a[2], bf[2];
#pragma unroll
      for (int mr = 0; mr < 2; ++mr)
        a[mr] = *(const short8*)&Ps[wr * 32 + mr * 16 + l16][kb];
#pragma unroll
      for (int nc = 0; nc < 2; ++nc)
        bf[nc] = *(const short8*)&Vts[wc * 32 + nc * 16 + l16][kb];
#pragma unroll
      for (int mr = 0; mr < 2; ++mr)
#pragma unroll
        for (int nc = 0; nc < 2; ++nc)
          acc[mr][nc] = __builtin_amdgcn_mfma_f32_16x16x32_bf16(a[mr], bf[nc], acc[mr][nc], 0, 0, 0);
    }
  }

// epilogue: bf16 write [b, s, h*64 + d]
#pragma unroll
  for (int mr = 0; mr < 2; ++mr)
#pragma unroll
    for (int nc = 0; nc < 2; ++nc)
#pragma unroll
      for (int jj = 0; jj < 4; ++jj) {
        const int i = i0 + wr * 32 + mr * 16 + lq * 4 + jj;
        const int d = wc * 32 + nc * 16 + l16;
        attn_out[((size_t)(b * SS + i)) * HID + h * HD + d] = f2bf(acc[mr][nc][jj]);
      }
}

// ---------------------------------------------------------------------------
// Residual + LayerNorm
// ---------------------------------------------------------------------------
__global__ __launch_bounds__(256) void ln_kernel(const float* __restrict__ proj,
                                                 const float* __restrict__ query,
                                                 const float* __restrict__ gamma,
                                                 const float* __restrict__ beta,
                                                 float* __restrict__ out) {
  const int row = blockIdx.x;
  const int tid = threadIdx.x;

  float x[2];
  float sum = 0.f, sumsq = 0.f;
#pragma unroll
  for (int t = 0; t < 2; ++t) {
    const int c = tid + t * 256;
    float v = proj[(size_t)row * HID + c] + query[(size_t)row * HID + c];
    x[t] = v;
    sum += v;
    sumsq += v * v;
  }
#pragma unroll
  for (int off = 1; off < 64; off <<= 1) {
    sum += __shfl_xor(sum, off);
    sumsq += __shfl_xor(sumsq, off);
  }
  __shared__ float s1[4], s2[4];
  if ((tid & 63) == 0) {
    s1[tid >> 6] = sum;
    s2[tid >> 6] = sumsq;
  }
  __syncthreads();
  sum = s1[0] + s1[1] + s1[2] + s1[3];
  sumsq = s2[0] + s2[1] + s2[2] + s2[3];
  const float mu = sum * (1.f / HID);
  const float var = sumsq * (1.f / HID) - mu * mu;
  const float rstd = rsqrtf(var + EPSV);
#pragma unroll
  for (int t = 0; t < 2; ++t) {
    const int c = tid + t * 256;
    out[(size_t)row * HID + c] = (x[t] - mu) * rstd * gamma[c] + beta[c];
  }
}

// ---------------------------------------------------------------------------
extern "C" void kernel_launch(void* const* d_in, const int* in_sizes, int n_in,
                              void* d_out, int out_size, void* d_ws, size_t ws_size,
                              hipStream_t stream) {
  const float* query = (const float*)d_in[0];
  const float* key = (const float*)d_in[1];
  const float* value = (const float*)d_in[2];
  const int* mask = (const int*)d_in[3];
  const float* Wq = (const float*)d_in[4];
  const float* bq = (const float*)d_in[5];
  const float* Wk = (const float*)d_in[6];
  const float* bk = (const float*)d_in[7];
  const float* Wv = (const float*)d_in[8];
  const float* bv = (const float*)d_in[9];
  const float* Wo = (const float*)d_in[10];
  const float* bo = (const float*)d_in[11];
  const float* temp = (const float*)d_in[12];
  const float* gamma = (const float*)d_in[13];
  const float* beta = (const float*)d_in[14];

  float* out_final = (float*)d_out;                     // (B,S,HID)
  float* attn = (float*)d_out + (size_t)BB * SS * HID;  // (B,H,S,S)

  // workspace layout (40.5 MB total)
  unsigned short* Qh = (unsigned short*)d_ws;    // f16 [bh][s][d]   8MB
  unsigned short* Kh = Qh + QKV_ELEMS;           // f16 [bh][s][d]   8MB
  unsigned short* Vt = Kh + QKV_ELEMS;           // bf16 [bh][d][s]  8MB
  unsigned short* aout = Vt + QKV_ELEMS;         // bf16 [b*s][512]  8MB
  float* stats = (float*)(aout + QKV_ELEMS);     // 2 * TOTROWS      0.5MB
  float* msnap = stats + 2 * TOTROWS;            // NJT * TOTROWS    8MB
  float* proj = (float*)d_ws;                    // f32, aliases Qh+Kh (16MB)

  const dim3 blk(256);
  const dim3 ggrid(HID / 128, NROWS / 128);  // 4 x 64

  gemm_bf16<3, false><<<ggrid, blk, 0, stream>>>(query, Wq, bq, Qh);
  gemm_bf16<3, false><<<ggrid, blk, 0, stream>>>(key, Wk, bk, Kh);
  gemm_bf16<2, false><<<ggrid, blk, 0, stream>>>(value, Wv, bv, Vt);

  const dim3 sgrid(SS / 64, BB * NH);  // 32 x 32
  scores_kernel<<<sgrid, blk, 0, stream>>>(Qh, Kh, mask, temp, attn, stats, msnap);
  attn_pv_kernel<<<sgrid, blk, 0, stream>>>(Vt, stats, msnap, attn, aout);

  gemm_bf16<0, true><<<ggrid, blk, 0, stream>>>(aout, Wo, bo, proj);
  ln_kernel<<<NROWS, blk, 0, stream>>>(proj, query, gamma, beta, out_final);
}

// Round 7
// 921.702 us; speedup vs baseline: 4.9816x; 1.0073x over previous
//
#include <hip/hip_runtime.h>
#include <math.h>

#define BB 4
#define SS 2048
#define NH 8
#define HD 64
#define HID 512
#define EPSV 1e-5f

#define NROWS (BB * SS)                // 8192 (b,s) rows
#define QKV_ELEMS (BB * NH * SS * HD)  // 4,194,304
#define TOTROWS (BB * NH * SS)         // 65536 (b,h,s) rows
#define NJT 16                         // j-tiles of 128 in scores

typedef __attribute__((ext_vector_type(8))) short short8;
typedef __attribute__((ext_vector_type(4))) float f32x4;
typedef _Float16 half2v __attribute__((ext_vector_type(2)));

__device__ __forceinline__ unsigned short f2bf(float f) {
  unsigned u = __builtin_bit_cast(unsigned, f);
  u += 0x7fff + ((u >> 16) & 1);  // RNE
  return (unsigned short)(u >> 16);
}

// |a-b| for 2 packed f16, accumulated into f32 via v_dot2_f32_f16
__device__ __forceinline__ float absdiff2(unsigned qa, unsigned kb, float acc,
                                          half2v ones) {
  half2v d = __builtin_bit_cast(half2v, qa) - __builtin_bit_cast(half2v, kb);
  unsigned au = __builtin_bit_cast(unsigned, d) & 0x7fff7fffu;
  return __builtin_amdgcn_fdot2(__builtin_bit_cast(half2v, au), ones, acc, false);
}

// ---------------------------------------------------------------------------
// bf16-MFMA GEMM: C = A(M x 512) @ W(512 x 512)^T + bias.
// 128x128 tile, 256 threads (4 waves, 2x2 quadrants of 64x64), K-step 32.
// ABF16: A is bf16 (ushort) in gmem; else f32 (converted during staging).
// MODE 0: C f32 [m][n].
// MODE 2: C bf16 transposed per head [bh][d][s] (V -> PV B-operand).
// MODE 3: C f16 split-head [bh][s][d] (Q, K for scores).
// ---------------------------------------------------------------------------
template <int MODE, bool ABF16>
__global__ __launch_bounds__(256, 2) void gemm_bf16(const void* __restrict__ Ain,
                                                    const float* __restrict__ W,
                                                    const float* __restrict__ bias,
                                                    void* __restrict__ Cout) {
  __shared__ unsigned short As[128][40];  // 32 k + 8 pad
  __shared__ unsigned short Ws[128][40];
  const int m0 = blockIdx.y * 128;
  const int n0 = blockIdx.x * 128;
  const int tid = threadIdx.x;
  const int lane = tid & 63;
  const int w = tid >> 6;
  const int wr = w >> 1;
  const int wc = w & 1;
  const int l16 = lane & 15;
  const int lq = lane >> 4;

  f32x4 acc[4][4];
#pragma unroll
  for (int mr = 0; mr < 4; ++mr)
#pragma unroll
    for (int nc = 0; nc < 4; ++nc) acc[mr][nc] = (f32x4)0.f;

  for (int k0 = 0; k0 < HID; k0 += 32) {
    __syncthreads();
    if (ABF16) {
      const unsigned short* A = (const unsigned short*)Ain;
#pragma unroll
      for (int p = 0; p < 2; ++p) {
        int idx = tid + p * 256;
        int row = idx >> 2;
        int ch = (idx & 3) * 8;
        *(uint4*)&As[row][ch] = *(const uint4*)&A[(size_t)(m0 + row) * HID + k0 + ch];
      }
#pragma unroll
      for (int p = 0; p < 4; ++p) {
        int idx = tid + p * 256;
        int row = idx >> 3;
        int c4 = (idx & 7) * 4;
        float4 wv = *(const float4*)&W[(size_t)(n0 + row) * HID + k0 + c4];
        ushort4 wb = {f2bf(wv.x), f2bf(wv.y), f2bf(wv.z), f2bf(wv.w)};
        *(ushort4*)&Ws[row][c4] = wb;
      }
    } else {
      const float* A = (const float*)Ain;
#pragma unroll
      for (int p = 0; p < 4; ++p) {
        int idx = tid + p * 256;
        int row = idx >> 3;
        int c4 = (idx & 7) * 4;
        float4 av = *(const float4*)&A[(size_t)(m0 + row) * HID + k0 + c4];
        float4 wv = *(const float4*)&W[(size_t)(n0 + row) * HID + k0 + c4];
        ushort4 ab = {f2bf(av.x), f2bf(av.y), f2bf(av.z), f2bf(av.w)};
        ushort4 wb = {f2bf(wv.x), f2bf(wv.y), f2bf(wv.z), f2bf(wv.w)};
        *(ushort4*)&As[row][c4] = ab;
        *(ushort4*)&Ws[row][c4] = wb;
      }
    }
    __syncthreads();
    const int kb = lq * 8;
    short8 a[4], b[4];
#pragma unroll
    for (int mr = 0; mr < 4; ++mr)
      a[mr] = *(const short8*)&As[wr * 64 + mr * 16 + l16][kb];
#pragma unroll
    for (int nc = 0; nc < 4; ++nc)
      b[nc] = *(const short8*)&Ws[wc * 64 + nc * 16 + l16][kb];
#pragma unroll
    for (int mr = 0; mr < 4; ++mr)
#pragma unroll
      for (int nc = 0; nc < 4; ++nc)
        acc[mr][nc] = __builtin_amdgcn_mfma_f32_16x16x32_bf16(a[mr], b[nc], acc[mr][nc], 0, 0, 0);
  }

#pragma unroll
  for (int nc = 0; nc < 4; ++nc) {
    const int n = n0 + wc * 64 + nc * 16 + l16;
    const float bv = bias[n];
#pragma unroll
    for (int mr = 0; mr < 4; ++mr) {
#pragma unroll
      for (int jj = 0; jj < 4; ++jj) {
        const int m = m0 + wr * 64 + mr * 16 + lq * 4 + jj;
        float v = acc[mr][nc][jj] + bv;
        if (MODE == 0) {
          ((float*)Cout)[(size_t)m * HID + n] = v;
        } else if (MODE == 2) {  // bf16 [bh][d][s]
          const int b_ = m >> 11, s = m & (SS - 1);
          const int h = n >> 6, d = n & 63;
          ((unsigned short*)Cout)[(((size_t)(b_ * NH + h)) * HD + d) * SS + s] = f2bf(v);
        } else {  // MODE 3: f16 [bh][s][d]
          const int b_ = m >> 11, s = m & (SS - 1);
          const int h = n >> 6, d = n & 63;
          _Float16 hv = (_Float16)v;
          ((unsigned short*)Cout)[(((size_t)(b_ * NH + h)) * SS + s) * HD + d] =
              __builtin_bit_cast(unsigned short, hv);
        }
      }
    }
  }
}

// ---------------------------------------------------------------------------
// Scores pass: 64-row i-tile, 128-col j-tiles, 512 threads (8 waves),
// 4x4 micro-tile per thread (rows ty+16r, cols tx+32c; ty=tid>>5, tx=tid&31).
// Q,K f16 [bh][s][d]. dist via packed-f16 sub + and-abs + v_dot2_f32_f16.
// __launch_bounds__(512,8): VGPR<=64 (live set ~55, round-6 fit in 44) so
// 8 waves/SIMD -> 32 waves/CU (grid = 1024 blocks = 4 blocks/CU x 8 waves).
// ---------------------------------------------------------------------------
__global__ __launch_bounds__(512, 8) void scores_kernel(
    const unsigned short* __restrict__ Qh, const unsigned short* __restrict__ Kh,
    const int* __restrict__ mask, const float* __restrict__ temp,
    float* __restrict__ attn, float* __restrict__ stats,
    float* __restrict__ msnap) {
  __shared__ unsigned short Qs[64][72];   // 64 f16 + 8 pad (144B rows)
  __shared__ unsigned short Ks[128][72];
  __shared__ int Ms[128];

  const int bh = blockIdx.y;
  const int b = bh >> 3;
  const int h = bh & 7;
  const int i0 = blockIdx.x * 64;
  const int tid = threadIdx.x;
  const int ty = tid >> 5;  // 0..15 (rows ty+16r, r=0..3)
  const int tx = tid & 31;  // 0..31 (cols tx+32c, c=0..3)
  const float tmp = temp[h];
  const half2v ones = {(_Float16)1.0f, (_Float16)1.0f};

  const unsigned short* Qb = Qh + (size_t)bh * SS * HD;
  const unsigned short* Kb = Kh + (size_t)bh * SS * HD;
  float* attn_b = attn + (size_t)bh * SS * SS;

  // stage Q tile once: 64 x 64 f16 = 512 uint4 chunks (1 per thread)
  {
    int row = tid >> 3;
    int ch = (tid & 7) * 8;
    *(uint4*)&Qs[row][ch] = *(const uint4*)&Qb[(size_t)(i0 + row) * HD + ch];
  }

  float m[4], sg[4];
#pragma unroll
  for (int r = 0; r < 4; ++r) {
    m[r] = -INFINITY;
    sg[r] = 0.f;
  }

  for (int j0 = 0; j0 < SS; j0 += 128) {
    __syncthreads();
// stage K tile: 128 x 64 f16 = 1024 uint4 chunks (2 per thread)
#pragma unroll
    for (int p = 0; p < 2; ++p) {
      int idx = tid + p * 512;
      int row = idx >> 3;
      int ch = (idx & 7) * 8;
      *(uint4*)&Ks[row][ch] = *(const uint4*)&Kb[(size_t)(j0 + row) * HD + ch];
    }
    if (tid < 128) Ms[tid] = mask[b * SS + j0 + tid];
    __syncthreads();

    float dist[4][4];
#pragma unroll
    for (int r = 0; r < 4; ++r)
#pragma unroll
      for (int c = 0; c < 4; ++c) dist[r][c] = 0.f;

// 8 chunks of 8 d-values (uint4 = 4 dwords of packed f16); unroll 2 keeps
// the load batch (and VGPR footprint) small.
#pragma unroll 2
    for (int k8 = 0; k8 < 8; ++k8) {
      uint4 q[4];
#pragma unroll
      for (int r = 0; r < 4; ++r) q[r] = *(const uint4*)&Qs[ty + 16 * r][k8 * 8];
#pragma unroll
      for (int c = 0; c < 4; ++c) {
        const uint4 kx = *(const uint4*)&Ks[tx + 32 * c][k8 * 8];
#pragma unroll
        for (int r = 0; r < 4; ++r) {
          float d = dist[r][c];
          d = absdiff2(q[r].x, kx.x, d, ones);
          d = absdiff2(q[r].y, kx.y, d, ones);
          d = absdiff2(q[r].z, kx.z, d, ones);
          d = absdiff2(q[r].w, kx.w, d, ones);
          dist[r][c] = d;
        }
      }
    }

    int msk[4];
#pragma unroll
    for (int c = 0; c < 4; ++c) msk[c] = Ms[tx + 32 * c];

    const int jt = j0 >> 7;
#pragma unroll
    for (int r = 0; r < 4; ++r) {
      float s[4];
      float rmax = -INFINITY;
#pragma unroll
      for (int c = 0; c < 4; ++c) {
        float sc = -dist[r][c] * tmp;
        if (msk[c] == 0) sc = -1e9f;
        s[c] = sc;
        rmax = fmaxf(rmax, sc);
      }
// make row max uniform across the 32 tx lanes
#pragma unroll
      for (int off = 1; off < 32; off <<= 1) rmax = fmaxf(rmax, __shfl_xor(rmax, off));
      const float mnew = fmaxf(m[r], rmax);
      const int i = i0 + ty + 16 * r;
      float* arow = attn_b + (size_t)i * SS + j0;
      float psum = 0.f;
#pragma unroll
      for (int c = 0; c < 4; ++c) {
        float pv = __expf(s[c] - mnew);
        psum += pv;
        arow[tx + 32 * c] = pv;  // store p'
      }
      sg[r] = sg[r] * __expf(m[r] - mnew) + psum;
      m[r] = mnew;
      if (tx == 0) msnap[((size_t)bh * NJT + jt) * SS + i] = mnew;
    }
  }

#pragma unroll
  for (int r = 0; r < 4; ++r) {
    float ssum = sg[r];
#pragma unroll
    for (int off = 1; off < 32; off <<= 1) ssum += __shfl_xor(ssum, off);
    if (tx == 0) {
      const int row = bh * SS + i0 + ty + 16 * r;
      stats[2 * row] = m[r];
      stats[2 * row + 1] = ssum;
    }
  }
}

// ---------------------------------------------------------------------------
// attn_pv: p = p' * exp(msnap - mfin) / sum ; rewrite attn f32 in place;
// PV via bf16 MFMA with pre-transposed V (Vt bf16 [bh][d][s]).
// 64x64 tiles for occupancy (19 KB LDS, grid 1024).
// ---------------------------------------------------------------------------
__global__ __launch_bounds__(256, 4) void attn_pv_kernel(
    const unsigned short* __restrict__ Vt, const float* __restrict__ stats,
    const float* __restrict__ msnap, float* __restrict__ attn,
    unsigned short* __restrict__ attn_out) {
  __shared__ unsigned short Ps[64][72];
  __shared__ unsigned short Vts[64][72];
  __shared__ float corr_s[64];

  const int bh = blockIdx.y;
  const int b = bh >> 3;
  const int h = bh & 7;
  const int i0 = blockIdx.x * 64;
  const int tid = threadIdx.x;
  const int lane = tid & 63;
  const int w = tid >> 6;
  const int wr = w >> 1;
  const int wc = w & 1;
  const int l16 = lane & 15;
  const int lq = lane >> 4;

  float* attn_b = attn + (size_t)bh * SS * SS;
  const unsigned short* Vtb = Vt + (size_t)bh * HD * SS;

  float mfin = 0.f, inv = 0.f;
  if (tid < 64) {
    const int row = bh * SS + i0 + tid;
    mfin = stats[2 * row];
    inv = 1.0f / stats[2 * row + 1];
  }

  f32x4 acc[2][2];
#pragma unroll
  for (int mr = 0; mr < 2; ++mr)
#pragma unroll
    for (int nc = 0; nc < 2; ++nc) acc[mr][nc] = (f32x4)0.f;

  for (int j0 = 0; j0 < SS; j0 += 64) {
    __syncthreads();
    if (tid < 64)
      corr_s[tid] =
          __expf(msnap[((size_t)bh * NJT + (j0 >> 7)) * SS + i0 + tid] - mfin) * inv;
// stage Vt tile: 64 d-rows x 64 j-cols bf16 = 512 uint4 chunks
#pragma unroll
    for (int p = 0; p < 2; ++p) {
      int idx = tid + p * 256;
      int row = idx >> 3;
      int ch = (idx & 7) * 8;
      *(uint4*)&Vts[row][ch] = *(const uint4*)&Vtb[(size_t)row * SS + j0 + ch];
    }
    __syncthreads();
// p-phase: 64x64 f32 RMW = 1024 float4
#pragma unroll
    for (int p = 0; p < 4; ++p) {
      int idx = tid + p * 256;
      int row = idx >> 4;
      int c4 = (idx & 15) * 4;
      float* ap = &attn_b[(size_t)(i0 + row) * SS + j0 + c4];
      float4 pv = *(float4*)ap;
      const float cr = corr_s[row];
      pv.x *= cr;
      pv.y *= cr;
      pv.z *= cr;
      pv.w *= cr;
      *(float4*)ap = pv;
      ushort4 pb = {f2bf(pv.x), f2bf(pv.y), f2bf(pv.z), f2bf(pv.w)};
      *(ushort4*)&Ps[row][c4] = pb;
    }
    __syncthreads();
// MFMA: out(64x64) += P(64x64) @ V(64x64)
#pragma unroll
    for (int ks = 0; ks < 2; ++ks) {
      const int kb = ks * 32 + lq * 8;
      short8 a[2], bf[2];
#pragma unroll
      for (int mr = 0; mr < 2; ++mr)
        a[mr] = *(const short8*)&Ps[wr * 32 + mr * 16 + l16][kb];
#pragma unroll
      for (int nc = 0; nc < 2; ++nc)
        bf[nc] = *(const short8*)&Vts[wc * 32 + nc * 16 + l16][kb];
#pragma unroll
      for (int mr = 0; mr < 2; ++mr)
#pragma unroll
        for (int nc = 0; nc < 2; ++nc)
          acc[mr][nc] = __builtin_amdgcn_mfma_f32_16x16x32_bf16(a[mr], bf[nc], acc[mr][nc], 0, 0, 0);
    }
  }

// epilogue: bf16 write [b, s, h*64 + d]
#pragma unroll
  for (int mr = 0; mr < 2; ++mr)
#pragma unroll
    for (int nc = 0; nc < 2; ++nc)
#pragma unroll
      for (int jj = 0; jj < 4; ++jj) {
        const int i = i0 + wr * 32 + mr * 16 + lq * 4 + jj;
        const int d = wc * 32 + nc * 16 + l16;
        attn_out[((size_t)(b * SS + i)) * HID + h * HD + d] = f2bf(acc[mr][nc][jj]);
      }
}

// ---------------------------------------------------------------------------
// Residual + LayerNorm
// ---------------------------------------------------------------------------
__global__ __launch_bounds__(256) void ln_kernel(const float* __restrict__ proj,
                                                 const float* __restrict__ query,
                                                 const float* __restrict__ gamma,
                                                 const float* __restrict__ beta,
                                                 float* __restrict__ out) {
  const int row = blockIdx.x;
  const int tid = threadIdx.x;

  float x[2];
  float sum = 0.f, sumsq = 0.f;
#pragma unroll
  for (int t = 0; t < 2; ++t) {
    const int c = tid + t * 256;
    float v = proj[(size_t)row * HID + c] + query[(size_t)row * HID + c];
    x[t] = v;
    sum += v;
    sumsq += v * v;
  }
#pragma unroll
  for (int off = 1; off < 64; off <<= 1) {
    sum += __shfl_xor(sum, off);
    sumsq += __shfl_xor(sumsq, off);
  }
  __shared__ float s1[4], s2[4];
  if ((tid & 63) == 0) {
    s1[tid >> 6] = sum;
    s2[tid >> 6] = sumsq;
  }
  __syncthreads();
  sum = s1[0] + s1[1] + s1[2] + s1[3];
  sumsq = s2[0] + s2[1] + s2[2] + s2[3];
  const float mu = sum * (1.f / HID);
  const float var = sumsq * (1.f / HID) - mu * mu;
  const float rstd = rsqrtf(var + EPSV);
#pragma unroll
  for (int t = 0; t < 2; ++t) {
    const int c = tid + t * 256;
    out[(size_t)row * HID + c] = (x[t] - mu) * rstd * gamma[c] + beta[c];
  }
}

// ---------------------------------------------------------------------------
extern "C" void kernel_launch(void* const* d_in, const int* in_sizes, int n_in,
                              void* d_out, int out_size, void* d_ws, size_t ws_size,
                              hipStream_t stream) {
  const float* query = (const float*)d_in[0];
  const float* key = (const float*)d_in[1];
  const float* value = (const float*)d_in[2];
  const int* mask = (const int*)d_in[3];
  const float* Wq = (const float*)d_in[4];
  const float* bq = (const float*)d_in[5];
  const float* Wk = (const float*)d_in[6];
  const float* bk = (const float*)d_in[7];
  const float* Wv = (const float*)d_in[8];
  const float* bv = (const float*)d_in[9];
  const float* Wo = (const float*)d_in[10];
  const float* bo = (const float*)d_in[11];
  const float* temp = (const float*)d_in[12];
  const float* gamma = (const float*)d_in[13];
  const float* beta = (const float*)d_in[14];

  float* out_final = (float*)d_out;                     // (B,S,HID)
  float* attn = (float*)d_out + (size_t)BB * SS * HID;  // (B,H,S,S)

  // workspace layout (36.5 MB total)
  unsigned short* Qh = (unsigned short*)d_ws;    // f16 [bh][s][d]   8MB
  unsigned short* Kh = Qh + QKV_ELEMS;           // f16 [bh][s][d]   8MB
  unsigned short* Vt = Kh + QKV_ELEMS;           // bf16 [bh][d][s]  8MB
  unsigned short* aout = Vt + QKV_ELEMS;         // bf16 [b*s][512]  8MB
  float* stats = (float*)(aout + QKV_ELEMS);     // 2 * TOTROWS      0.5MB
  float* msnap = stats + 2 * TOTROWS;            // NJT * TOTROWS    4MB
  float* proj = (float*)d_ws;                    // f32, aliases Qh+Kh (16MB)

  const dim3 blk(256);
  const dim3 ggrid(HID / 128, NROWS / 128);  // 4 x 64

  gemm_bf16<3, false><<<ggrid, blk, 0, stream>>>(query, Wq, bq, Qh);
  gemm_bf16<3, false><<<ggrid, blk, 0, stream>>>(key, Wk, bk, Kh);
  gemm_bf16<2, false><<<ggrid, blk, 0, stream>>>(value, Wv, bv, Vt);

  const dim3 sgrid(SS / 64, BB * NH);  // 32 x 32
  scores_kernel<<<sgrid, dim3(512), 0, stream>>>(Qh, Kh, mask, temp, attn, stats, msnap);
  attn_pv_kernel<<<sgrid, blk, 0, stream>>>(Vt, stats, msnap, attn, aout);

  gemm_bf16<0, true><<<ggrid, blk, 0, stream>>>(aout, Wo, bo, proj);
  ln_kernel<<<NROWS, blk, 0, stream>>>(proj, query, gamma, beta, out_final);
}

// Round 8
// 913.737 us; speedup vs baseline: 5.0250x; 1.0087x over previous
//
#include <hip/hip_runtime.h>
#include <math.h>

#define BB 4
#define SS 2048
#define NH 8
#define HD 64
#define HID 512
#define EPSV 1e-5f

#define NROWS (BB * SS)                // 8192 (b,s) rows
#define QKV_ELEMS (BB * NH * SS * HD)  // 4,194,304
#define TOTROWS (BB * NH * SS)         // 65536 (b,h,s) rows
#define NJT 16                         // j-tiles of 128 in scores

typedef __attribute__((ext_vector_type(8))) short short8;
typedef __attribute__((ext_vector_type(4))) float f32x4;

__device__ __forceinline__ unsigned short f2bf(float f) {
  unsigned u = __builtin_bit_cast(unsigned, f);
  u += 0x7fff + ((u >> 16) & 1);  // RNE
  return (unsigned short)(u >> 16);
}

// |a-b| for 2 packed f16 accumulated into f32 — pinned codegen: exactly
// v_pk_add_f16(neg) + v_and_b32 + v_dot2_f32_f16 (3 instr / 2 elements).
__device__ __forceinline__ float absdiff2(unsigned qa, unsigned kb, float acc,
                                          unsigned ones) {
  unsigned d, ad;
  asm("v_pk_add_f16 %0, %1, %2 neg_lo:[0,1] neg_hi:[0,1]"
      : "=v"(d)
      : "v"(qa), "v"(kb));
  asm("v_and_b32 %0, 0x7fff7fff, %1" : "=v"(ad) : "v"(d));
  asm("v_dot2_f32_f16 %0, %1, %2, %0" : "+v"(acc) : "v"(ad), "v"(ones));
  return acc;
}

// ---------------------------------------------------------------------------
// bf16-MFMA GEMM: C = A(M x 512) @ W(512 x 512)^T + bias.
// 128x128 tile, 256 threads (4 waves, 2x2 quadrants of 64x64), K-step 32.
// ABF16: A is bf16 (ushort) in gmem; else f32 (converted during staging).
// MODE 0: C f32 [m][n].
// MODE 2: C bf16 transposed per head [bh][d][s] (V -> PV B-operand).
// MODE 3: C f16 split-head [bh][s][d] (Q, K for scores).
// ---------------------------------------------------------------------------
template <int MODE, bool ABF16>
__global__ __launch_bounds__(256, 2) void gemm_bf16(const void* __restrict__ Ain,
                                                    const float* __restrict__ W,
                                                    const float* __restrict__ bias,
                                                    void* __restrict__ Cout) {
  __shared__ unsigned short As[128][40];  // 32 k + 8 pad
  __shared__ unsigned short Ws[128][40];
  const int m0 = blockIdx.y * 128;
  const int n0 = blockIdx.x * 128;
  const int tid = threadIdx.x;
  const int lane = tid & 63;
  const int w = tid >> 6;
  const int wr = w >> 1;
  const int wc = w & 1;
  const int l16 = lane & 15;
  const int lq = lane >> 4;

  f32x4 acc[4][4];
#pragma unroll
  for (int mr = 0; mr < 4; ++mr)
#pragma unroll
    for (int nc = 0; nc < 4; ++nc) acc[mr][nc] = (f32x4)0.f;

  for (int k0 = 0; k0 < HID; k0 += 32) {
    __syncthreads();
    if (ABF16) {
      const unsigned short* A = (const unsigned short*)Ain;
#pragma unroll
      for (int p = 0; p < 2; ++p) {
        int idx = tid + p * 256;
        int row = idx >> 2;
        int ch = (idx & 3) * 8;
        *(uint4*)&As[row][ch] = *(const uint4*)&A[(size_t)(m0 + row) * HID + k0 + ch];
      }
#pragma unroll
      for (int p = 0; p < 4; ++p) {
        int idx = tid + p * 256;
        int row = idx >> 3;
        int c4 = (idx & 7) * 4;
        float4 wv = *(const float4*)&W[(size_t)(n0 + row) * HID + k0 + c4];
        ushort4 wb = {f2bf(wv.x), f2bf(wv.y), f2bf(wv.z), f2bf(wv.w)};
        *(ushort4*)&Ws[row][c4] = wb;
      }
    } else {
      const float* A = (const float*)Ain;
#pragma unroll
      for (int p = 0; p < 4; ++p) {
        int idx = tid + p * 256;
        int row = idx >> 3;
        int c4 = (idx & 7) * 4;
        float4 av = *(const float4*)&A[(size_t)(m0 + row) * HID + k0 + c4];
        float4 wv = *(const float4*)&W[(size_t)(n0 + row) * HID + k0 + c4];
        ushort4 ab = {f2bf(av.x), f2bf(av.y), f2bf(av.z), f2bf(av.w)};
        ushort4 wb = {f2bf(wv.x), f2bf(wv.y), f2bf(wv.z), f2bf(wv.w)};
        *(ushort4*)&As[row][c4] = ab;
        *(ushort4*)&Ws[row][c4] = wb;
      }
    }
    __syncthreads();
    const int kb = lq * 8;
    short8 a[4], b[4];
#pragma unroll
    for (int mr = 0; mr < 4; ++mr)
      a[mr] = *(const short8*)&As[wr * 64 + mr * 16 + l16][kb];
#pragma unroll
    for (int nc = 0; nc < 4; ++nc)
      b[nc] = *(const short8*)&Ws[wc * 64 + nc * 16 + l16][kb];
#pragma unroll
    for (int mr = 0; mr < 4; ++mr)
#pragma unroll
      for (int nc = 0; nc < 4; ++nc)
        acc[mr][nc] = __builtin_amdgcn_mfma_f32_16x16x32_bf16(a[mr], b[nc], acc[mr][nc], 0, 0, 0);
  }

#pragma unroll
  for (int nc = 0; nc < 4; ++nc) {
    const int n = n0 + wc * 64 + nc * 16 + l16;
    const float bv = bias[n];
#pragma unroll
    for (int mr = 0; mr < 4; ++mr) {
#pragma unroll
      for (int jj = 0; jj < 4; ++jj) {
        const int m = m0 + wr * 64 + mr * 16 + lq * 4 + jj;
        float v = acc[mr][nc][jj] + bv;
        if (MODE == 0) {
          ((float*)Cout)[(size_t)m * HID + n] = v;
        } else if (MODE == 2) {  // bf16 [bh][d][s]
          const int b_ = m >> 11, s = m & (SS - 1);
          const int h = n >> 6, d = n & 63;
          ((unsigned short*)Cout)[(((size_t)(b_ * NH + h)) * HD + d) * SS + s] = f2bf(v);
        } else {  // MODE 3: f16 [bh][s][d]
          const int b_ = m >> 11, s = m & (SS - 1);
          const int h = n >> 6, d = n & 63;
          _Float16 hv = (_Float16)v;
          ((unsigned short*)Cout)[(((size_t)(b_ * NH + h)) * SS + s) * HD + d] =
              __builtin_bit_cast(unsigned short, hv);
        }
      }
    }
  }
}

// ---------------------------------------------------------------------------
// Scores pass: 64-row i-tile, 128-col j-tiles, 512 threads (8 waves),
// 4x4 micro-tile per thread (rows ty+16r, cols tx+32c; ty=tid>>5, tx=tid&31).
// Q,K f16 [bh][s][d]. dist via pinned-asm pk_sub/and/dot2 (3 instr per dword).
// ---------------------------------------------------------------------------
__global__ __launch_bounds__(512, 8) void scores_kernel(
    const unsigned short* __restrict__ Qh, const unsigned short* __restrict__ Kh,
    const int* __restrict__ mask, const float* __restrict__ temp,
    float* __restrict__ attn, float* __restrict__ stats,
    float* __restrict__ msnap) {
  __shared__ unsigned short Qs[64][72];   // 64 f16 + 8 pad (144B rows)
  __shared__ unsigned short Ks[128][72];
  __shared__ int Ms[128];

  const int bh = blockIdx.y;
  const int b = bh >> 3;
  const int h = bh & 7;
  const int i0 = blockIdx.x * 64;
  const int tid = threadIdx.x;
  const int ty = tid >> 5;  // 0..15 (rows ty+16r, r=0..3)
  const int tx = tid & 31;  // 0..31 (cols tx+32c, c=0..3)
  const float tmp = temp[h];
  const unsigned ones = 0x3C003C00u;  // packed f16 (1.0, 1.0)

  const unsigned short* Qb = Qh + (size_t)bh * SS * HD;
  const unsigned short* Kb = Kh + (size_t)bh * SS * HD;
  float* attn_b = attn + (size_t)bh * SS * SS;

  // stage Q tile once: 64 x 64 f16 = 512 uint4 chunks (1 per thread)
  {
    int row = tid >> 3;
    int ch = (tid & 7) * 8;
    *(uint4*)&Qs[row][ch] = *(const uint4*)&Qb[(size_t)(i0 + row) * HD + ch];
  }

  float m[4], sg[4];
#pragma unroll
  for (int r = 0; r < 4; ++r) {
    m[r] = -INFINITY;
    sg[r] = 0.f;
  }

  for (int j0 = 0; j0 < SS; j0 += 128) {
    __syncthreads();
// stage K tile: 128 x 64 f16 = 1024 uint4 chunks (2 per thread)
#pragma unroll
    for (int p = 0; p < 2; ++p) {
      int idx = tid + p * 512;
      int row = idx >> 3;
      int ch = (idx & 7) * 8;
      *(uint4*)&Ks[row][ch] = *(const uint4*)&Kb[(size_t)(j0 + row) * HD + ch];
    }
    if (tid < 128) Ms[tid] = mask[b * SS + j0 + tid];
    __syncthreads();

    float dist[4][4];
#pragma unroll
    for (int r = 0; r < 4; ++r)
#pragma unroll
      for (int c = 0; c < 4; ++c) dist[r][c] = 0.f;

// 8 chunks of 8 d-values (uint4 = 4 dwords of packed f16); unroll 2 keeps
// the load batch (and VGPR footprint) small.
#pragma unroll 2
    for (int k8 = 0; k8 < 8; ++k8) {
      uint4 q[4];
#pragma unroll
      for (int r = 0; r < 4; ++r) q[r] = *(const uint4*)&Qs[ty + 16 * r][k8 * 8];
#pragma unroll
      for (int c = 0; c < 4; ++c) {
        const uint4 kx = *(const uint4*)&Ks[tx + 32 * c][k8 * 8];
#pragma unroll
        for (int r = 0; r < 4; ++r) {
          float d = dist[r][c];
          d = absdiff2(q[r].x, kx.x, d, ones);
          d = absdiff2(q[r].y, kx.y, d, ones);
          d = absdiff2(q[r].z, kx.z, d, ones);
          d = absdiff2(q[r].w, kx.w, d, ones);
          dist[r][c] = d;
        }
      }
    }

    int msk[4];
#pragma unroll
    for (int c = 0; c < 4; ++c) msk[c] = Ms[tx + 32 * c];

    const int jt = j0 >> 7;
#pragma unroll
    for (int r = 0; r < 4; ++r) {
      float s[4];
      float rmax = -INFINITY;
#pragma unroll
      for (int c = 0; c < 4; ++c) {
        float sc = -dist[r][c] * tmp;
        if (msk[c] == 0) sc = -1e9f;
        s[c] = sc;
        rmax = fmaxf(rmax, sc);
      }
// make row max uniform across the 32 tx lanes
#pragma unroll
      for (int off = 1; off < 32; off <<= 1) rmax = fmaxf(rmax, __shfl_xor(rmax, off));
      const float mnew = fmaxf(m[r], rmax);
      const int i = i0 + ty + 16 * r;
      float* arow = attn_b + (size_t)i * SS + j0;
      float psum = 0.f;
#pragma unroll
      for (int c = 0; c < 4; ++c) {
        float pv = __expf(s[c] - mnew);
        psum += pv;
        arow[tx + 32 * c] = pv;  // store p'
      }
      sg[r] = sg[r] * __expf(m[r] - mnew) + psum;
      m[r] = mnew;
      if (tx == 0) msnap[((size_t)bh * NJT + jt) * SS + i] = mnew;
    }
  }

#pragma unroll
  for (int r = 0; r < 4; ++r) {
    float ssum = sg[r];
#pragma unroll
    for (int off = 1; off < 32; off <<= 1) ssum += __shfl_xor(ssum, off);
    if (tx == 0) {
      const int row = bh * SS + i0 + ty + 16 * r;
      stats[2 * row] = m[r];
      stats[2 * row + 1] = ssum;
    }
  }
}

// ---------------------------------------------------------------------------
// attn_pv: p = p' * exp(msnap - mfin) / sum ; rewrite attn f32 in place;
// PV via bf16 MFMA with pre-transposed V (Vt bf16 [bh][d][s]).
// 64x64 tiles for occupancy (19 KB LDS, grid 1024).
// ---------------------------------------------------------------------------
__global__ __launch_bounds__(256, 4) void attn_pv_kernel(
    const unsigned short* __restrict__ Vt, const float* __restrict__ stats,
    const float* __restrict__ msnap, float* __restrict__ attn,
    unsigned short* __restrict__ attn_out) {
  __shared__ unsigned short Ps[64][72];
  __shared__ unsigned short Vts[64][72];
  __shared__ float corr_s[64];

  const int bh = blockIdx.y;
  const int b = bh >> 3;
  const int h = bh & 7;
  const int i0 = blockIdx.x * 64;
  const int tid = threadIdx.x;
  const int lane = tid & 63;
  const int w = tid >> 6;
  const int wr = w >> 1;
  const int wc = w & 1;
  const int l16 = lane & 15;
  const int lq = lane >> 4;

  float* attn_b = attn + (size_t)bh * SS * SS;
  const unsigned short* Vtb = Vt + (size_t)bh * HD * SS;

  float mfin = 0.f, inv = 0.f;
  if (tid < 64) {
    const int row = bh * SS + i0 + tid;
    mfin = stats[2 * row];
    inv = 1.0f / stats[2 * row + 1];
  }

  f32x4 acc[2][2];
#pragma unroll
  for (int mr = 0; mr < 2; ++mr)
#pragma unroll
    for (int nc = 0; nc < 2; ++nc) acc[mr][nc] = (f32x4)0.f;

  for (int j0 = 0; j0 < SS; j0 += 64) {
    __syncthreads();
    if (tid < 64)
      corr_s[tid] =
          __expf(msnap[((size_t)bh * NJT + (j0 >> 7)) * SS + i0 + tid] - mfin) * inv;
// stage Vt tile: 64 d-rows x 64 j-cols bf16 = 512 uint4 chunks
#pragma unroll
    for (int p = 0; p < 2; ++p) {
      int idx = tid + p * 256;
      int row = idx >> 3;
      int ch = (idx & 7) * 8;
      *(uint4*)&Vts[row][ch] = *(const uint4*)&Vtb[(size_t)row * SS + j0 + ch];
    }
    __syncthreads();
// p-phase: 64x64 f32 RMW = 1024 float4
#pragma unroll
    for (int p = 0; p < 4; ++p) {
      int idx = tid + p * 256;
      int row = idx >> 4;
      int c4 = (idx & 15) * 4;
      float* ap = &attn_b[(size_t)(i0 + row) * SS + j0 + c4];
      float4 pv = *(float4*)ap;
      const float cr = corr_s[row];
      pv.x *= cr;
      pv.y *= cr;
      pv.z *= cr;
      pv.w *= cr;
      *(float4*)ap = pv;
      ushort4 pb = {f2bf(pv.x), f2bf(pv.y), f2bf(pv.z), f2bf(pv.w)};
      *(ushort4*)&Ps[row][c4] = pb;
    }
    __syncthreads();
// MFMA: out(64x64) += P(64x64) @ V(64x64)
#pragma unroll
    for (int ks = 0; ks < 2; ++ks) {
      const int kb = ks * 32 + lq * 8;
      short8 a[2], bf[2];
#pragma unroll
      for (int mr = 0; mr < 2; ++mr)
        a[mr] = *(const short8*)&Ps[wr * 32 + mr * 16 + l16][kb];
#pragma unroll
      for (int nc = 0; nc < 2; ++nc)
        bf[nc] = *(const short8*)&Vts[wc * 32 + nc * 16 + l16][kb];
#pragma unroll
      for (int mr = 0; mr < 2; ++mr)
#pragma unroll
        for (int nc = 0; nc < 2; ++nc)
          acc[mr][nc] = __builtin_amdgcn_mfma_f32_16x16x32_bf16(a[mr], bf[nc], acc[mr][nc], 0, 0, 0);
    }
  }

// epilogue: bf16 write [b, s, h*64 + d]
#pragma unroll
  for (int mr = 0; mr < 2; ++mr)
#pragma unroll
    for (int nc = 0; nc < 2; ++nc)
#pragma unroll
      for (int jj = 0; jj < 4; ++jj) {
        const int i = i0 + wr * 32 + mr * 16 + lq * 4 + jj;
        const int d = wc * 32 + nc * 16 + l16;
        attn_out[((size_t)(b * SS + i)) * HID + h * HD + d] = f2bf(acc[mr][nc][jj]);
      }
}

// ---------------------------------------------------------------------------
// Residual + LayerNorm
// ---------------------------------------------------------------------------
__global__ __launch_bounds__(256) void ln_kernel(const float* __restrict__ proj,
                                                 const float* __restrict__ query,
                                                 const float* __restrict__ gamma,
                                                 const float* __restrict__ beta,
                                                 float* __restrict__ out) {
  const int row = blockIdx.x;
  const int tid = threadIdx.x;

  float x[2];
  float sum = 0.f, sumsq = 0.f;
#pragma unroll
  for (int t = 0; t < 2; ++t) {
    const int c = tid + t * 256;
    float v = proj[(size_t)row * HID + c] + query[(size_t)row * HID + c];
    x[t] = v;
    sum += v;
    sumsq += v * v;
  }
#pragma unroll
  for (int off = 1; off < 64; off <<= 1) {
    sum += __shfl_xor(sum, off);
    sumsq += __shfl_xor(sumsq, off);
  }
  __shared__ float s1[4], s2[4];
  if ((tid & 63) == 0) {
    s1[tid >> 6] = sum;
    s2[tid >> 6] = sumsq;
  }
  __syncthreads();
  sum = s1[0] + s1[1] + s1[2] + s1[3];
  sumsq = s2[0] + s2[1] + s2[2] + s2[3];
  const float mu = sum * (1.f / HID);
  const float var = sumsq * (1.f / HID) - mu * mu;
  const float rstd = rsqrtf(var + EPSV);
#pragma unroll
  for (int t = 0; t < 2; ++t) {
    const int c = tid + t * 256;
    out[(size_t)row * HID + c] = (x[t] - mu) * rstd * gamma[c] + beta[c];
  }
}

// ---------------------------------------------------------------------------
extern "C" void kernel_launch(void* const* d_in, const int* in_sizes, int n_in,
                              void* d_out, int out_size, void* d_ws, size_t ws_size,
                              hipStream_t stream) {
  const float* query = (const float*)d_in[0];
  const float* key = (const float*)d_in[1];
  const float* value = (const float*)d_in[2];
  const int* mask = (const int*)d_in[3];
  const float* Wq = (const float*)d_in[4];
  const float* bq = (const float*)d_in[5];
  const float* Wk = (const float*)d_in[6];
  const float* bk = (const float*)d_in[7];
  const float* Wv = (const float*)d_in[8];
  const float* bv = (const float*)d_in[9];
  const float* Wo = (const float*)d_in[10];
  const float* bo = (const float*)d_in[11];
  const float* temp = (const float*)d_in[12];
  const float* gamma = (const float*)d_in[13];
  const float* beta = (const float*)d_in[14];

  float* out_final = (float*)d_out;                     // (B,S,HID)
  float* attn = (float*)d_out + (size_t)BB * SS * HID;  // (B,H,S,S)

  // workspace layout (36.5 MB total)
  unsigned short* Qh = (unsigned short*)d_ws;    // f16 [bh][s][d]   8MB
  unsigned short* Kh = Qh + QKV_ELEMS;           // f16 [bh][s][d]   8MB
  unsigned short* Vt = Kh + QKV_ELEMS;           // bf16 [bh][d][s]  8MB
  unsigned short* aout = Vt + QKV_ELEMS;         // bf16 [b*s][512]  8MB
  float* stats = (float*)(aout + QKV_ELEMS);     // 2 * TOTROWS      0.5MB
  float* msnap = stats + 2 * TOTROWS;            // NJT * TOTROWS    4MB
  float* proj = (float*)d_ws;                    // f32, aliases Qh+Kh (16MB)

  const dim3 blk(256);
  const dim3 ggrid(HID / 128, NROWS / 128);  // 4 x 64

  gemm_bf16<3, false><<<ggrid, blk, 0, stream>>>(query, Wq, bq, Qh);
  gemm_bf16<3, false><<<ggrid, blk, 0, stream>>>(key, Wk, bk, Kh);
  gemm_bf16<2, false><<<ggrid, blk, 0, stream>>>(value, Wv, bv, Vt);

  const dim3 sgrid(SS / 64, BB * NH);  // 32 x 32
  scores_kernel<<<sgrid, dim3(512), 0, stream>>>(Qh, Kh, mask, temp, attn, stats, msnap);
  attn_pv_kernel<<<sgrid, blk, 0, stream>>>(Vt, stats, msnap, attn, aout);

  gemm_bf16<0, true><<<ggrid, blk, 0, stream>>>(aout, Wo, bo, proj);
  ln_kernel<<<NROWS, blk, 0, stream>>>(proj, query, gamma, beta, out_final);
}